// Round 11
// baseline (3284.648 us; speedup 1.0000x reference)
//
#include <hip/hip_runtime.h>
#include <hip/hip_bf16.h>

// Problem constants (from reference)
constexpr int BB = 16;     // batches
constexpr int NN = 8192;   // points
constexpr int SS = 1024;   // samples (FPS)
constexpr int KK = 32;     // kNN
constexpr int BUFC = 256;  // per-wave candidate buffer (keys <= That)
constexpr int NBLK = 256;  // fused kernel grid = CU count (1 block/CU via LDS)
constexpr int NWORKW = (NBLK - BB) * 8;   // 1920 knn worker waves

__device__ __forceinline__ float b2f(__hip_bfloat16 h) { return __bfloat162float(h); }

// Monotone map f32 -> u32 (order-preserving, bijective; d is never -0 here).
__device__ __forceinline__ unsigned mkey32(float d) {
    unsigned u = __float_as_uint(d);
    return u ^ (0x80000000u | (unsigned)((int)u >> 31));
}

// DPP lane-move of a u64 (both halves move identically).
template <int CTRL, int RMASK>
__device__ __forceinline__ unsigned long long dppmove_u64(unsigned long long v) {
    int lo = (int)(unsigned)v, hi = (int)(unsigned)(v >> 32);
    int nlo = __builtin_amdgcn_update_dpp(lo, lo, CTRL, RMASK, 0xf, false);
    int nhi = __builtin_amdgcn_update_dpp(hi, hi, CTRL, RMASK, 0xf, false);
    return ((unsigned long long)(unsigned)nhi << 32) | (unsigned)nlo;
}

__device__ __forceinline__ unsigned long long u64max(unsigned long long a,
                                                     unsigned long long b) {
    return a > b ? a : b;
}

// Wave64 max-reduce via DPP. Lane 63 holds the max.
__device__ __forceinline__ unsigned long long wave_max_dpp(unsigned long long k) {
    k = u64max(k, dppmove_u64<0x121, 0xf>(k));  // row_ror:1
    k = u64max(k, dppmove_u64<0x122, 0xf>(k));  // row_ror:2
    k = u64max(k, dppmove_u64<0x124, 0xf>(k));  // row_ror:4
    k = u64max(k, dppmove_u64<0x128, 0xf>(k));  // row_ror:8
    k = u64max(k, dppmove_u64<0x142, 0xa>(k));  // row_bcast:15 -> rows 1,3
    k = u64max(k, dppmove_u64<0x143, 0xc>(k));  // row_bcast:31 -> rows 2,3
    return k;
}

// Cross-lane bitonic sort of 64 u64 keys (ascending); lane i ends with i-th smallest.
__device__ __forceinline__ unsigned long long bitonic64(unsigned long long v, int lane) {
#pragma unroll
    for (int k = 2; k <= 64; k <<= 1) {
#pragma unroll
        for (int j = k >> 1; j > 0; j >>= 1) {
            unsigned long long p = __shfl_xor(v, j);
            bool up = ((lane & k) == 0);
            bool lower = ((lane & j) == 0);
            bool take_min = (up == lower);
            v = take_min ? (p < v ? p : v) : (p > v ? p : v);
        }
    }
    return v;
}

// ---------------------------------------------------------------------------
// K0: dtype detection + upcast to f32 workspace + sentinel fill of d_out +
//     zero the FPS progress counters (prog aliases the tf region: tf is
//     written only by cdist, after the fused kernel completes).
// ---------------------------------------------------------------------------
__global__ __launch_bounds__(256) void convert_kernel(
    const void* __restrict__ xyz_raw, const void* __restrict__ g1r,
    const void* __restrict__ b1r, const void* __restrict__ g2r,
    const void* __restrict__ b2r, float* __restrict__ xyzf,
    float* __restrict__ params, void* __restrict__ out_raw,
    unsigned* __restrict__ prog) {
    const unsigned short* u = (const unsigned short*)xyz_raw;
    unsigned short s = u[2 * (threadIdx.x & 63)];
    int e = (s >> 7) & 0xFF;
    unsigned long long m = __ballot(e >= 100 && e <= 140);
    bool isbf = __popcll(m) > 48;

    const int NT = BB * NN * 3;
    int tid = blockIdx.x * blockDim.x + threadIdx.x;
    int stride = gridDim.x * blockDim.x;
    if (isbf) {
        const __hip_bfloat16* p = (const __hip_bfloat16*)xyz_raw;
        for (int i = tid; i < NT; i += stride) xyzf[i] = b2f(p[i]);
    } else {
        const float* p = (const float*)xyz_raw;
        for (int i = tid; i < NT; i += stride) xyzf[i] = p[i];
    }
    if (blockIdx.x == 0 && threadIdx.x < 85) {
        int t = threadIdx.x;
        if (t == 84) {
            params[84] = isbf ? 1.0f : 0.0f;
        } else {
            const void* src; int off;
            if (t < 6)       { src = g1r; off = t; }
            else if (t < 12) { src = b1r; off = t - 6; }
            else if (t < 48) { src = g2r; off = t - 12; }
            else             { src = b2r; off = t - 48; }
            params[t] = isbf ? b2f(((const __hip_bfloat16*)src)[off])
                             : ((const float*)src)[off];
        }
    }
    if (blockIdx.x == 1 && threadIdx.x < 64) {
        for (int i = threadIdx.x; i < 576; i += 64) {
            if (isbf) ((__hip_bfloat16*)out_raw)[i] = __float2bfloat16(1.0f);
            else      ((float*)out_raw)[i] = 1.0f;
        }
    }
    if (blockIdx.x == 2 && threadIdx.x < 256) {
        prog[threadIdx.x] = 0u;   // prog[b*16] used; zero whole 1KB
    }
}

// ---------------------------------------------------------------------------
// K1 (FUSED): FPS (blocks 0..15, r7 body verbatim) + persistent kNN workers
// (blocks 16..255) overlapped in ONE launch.
//  * Co-residency: 114.8 KB LDS/block -> exactly 1 block/CU; grid = 256 =
//    CU count -> all blocks resident, no dispatch-order dependence.
//  * FPS publishes each centroid with relaxed agent-scope atomic u32 stores
//    into new_xyz (same bits as before) then release-stores prog[b*16] =
//    step+1 (one 64B line per batch -> poll traffic spread over 16 lines).
//  * knn wave for query (b,s) acquire-polls prog[b*16] >= s+1 (lane 0 only,
//    s_sleep backoff, bounded guard -> hang-free even if the co-residency
//    assumption broke), then lane 0 atomically loads the 3 coord words and
//    shfl-broadcasts. kNN math body is r4's proven exact-selection code.
//  * fps never waits on knn: the handshake is off fps's critical path.
// ---------------------------------------------------------------------------
__global__ __attribute__((amdgpu_flat_work_group_size(512, 512)))
__attribute__((amdgpu_waves_per_eu(2, 2)))
void fps_knn_kernel(const float* __restrict__ xyzf,
                    float* __restrict__ new_xyz,
                    unsigned* __restrict__ prog,
                    float* __restrict__ A,
                    double* __restrict__ qstats) {
    __shared__ float sxyz[NN * 3];                 // 96 KB (fps branch)
    __shared__ unsigned long long skey[2][8];      // fps branch
    __shared__ unsigned long long buf[8][BUFC];    // 16 KB (knn branch)

    const int blk = blockIdx.x, t = threadIdx.x;
    const int wave = t >> 6, lane = t & 63;

    if (blk < BB) {
        // ================= FPS branch (r7 structure, publish added) ========
        constexpr int T = 512, P = NN / T;
        const int b = blk;
        const float* xb = xyzf + (size_t)b * NN * 3;

        float px[P], py[P], pz[P], ds[P];
#pragma unroll
        for (int j = 0; j < P; j++) {
            int p = t + j * T;
            px[j] = xb[p * 3 + 0];
            py[j] = xb[p * 3 + 1];
            pz[j] = xb[p * 3 + 2];
            ds[j] = 1e10f;
        }
        for (int i = t; i < NN * 3; i += T) sxyz[i] = xb[i];

        float cx = xb[0], cy = xb[1], cz = xb[2];
        if (t == 0) {
            unsigned* o = (unsigned*)(new_xyz + (size_t)b * SS * 3);
            __hip_atomic_store(&o[0], __float_as_uint(cx), __ATOMIC_RELAXED, __HIP_MEMORY_SCOPE_AGENT);
            __hip_atomic_store(&o[1], __float_as_uint(cy), __ATOMIC_RELAXED, __HIP_MEMORY_SCOPE_AGENT);
            __hip_atomic_store(&o[2], __float_as_uint(cz), __ATOMIC_RELAXED, __HIP_MEMORY_SCOPE_AGENT);
            __hip_atomic_store(&prog[b * 16], 1u, __ATOMIC_RELEASE, __HIP_MEMORY_SCOPE_AGENT);
        }
        __syncthreads();   // sxyz visible

        for (int step = 1; step < SS; step++) {
            float bv = -1.0f; int bj = 0;
#pragma unroll
            for (int j = 0; j < P; j++) {
                float dx = __fsub_rn(px[j], cx);
                float dy = __fsub_rn(py[j], cy);
                float dz = __fsub_rn(pz[j], cz);
                float d = __fadd_rn(__fadd_rn(__fmul_rn(dx, dx), __fmul_rn(dy, dy)), __fmul_rn(dz, dz));
                float mm = fminf(ds[j], d);
                ds[j] = mm;
                if (mm > bv) { bv = mm; bj = j; }   // first-max kept (lowest idx)
            }
            unsigned idx = (unsigned)(t + bj * T);
            unsigned long long key =
                ((unsigned long long)__float_as_uint(bv) << 32) | (unsigned)(~idx);

            key = wave_max_dpp(key);
            const int par = step & 1;
            if (lane == 63) skey[par][wave] = key;
            __syncthreads();

            unsigned long long k0 = u64max(skey[par][0], skey[par][1]);
            unsigned long long k1 = u64max(skey[par][2], skey[par][3]);
            unsigned long long k2 = u64max(skey[par][4], skey[par][5]);
            unsigned long long k3 = u64max(skey[par][6], skey[par][7]);
            unsigned long long bk = u64max(u64max(k0, k1), u64max(k2, k3));

            unsigned gidx = ~(unsigned)bk;
            cx = sxyz[gidx * 3 + 0];
            cy = sxyz[gidx * 3 + 1];
            cz = sxyz[gidx * 3 + 2];
            if (t == 0) {
                unsigned* o = (unsigned*)(new_xyz + ((size_t)b * SS + step) * 3);
                __hip_atomic_store(&o[0], __float_as_uint(cx), __ATOMIC_RELAXED, __HIP_MEMORY_SCOPE_AGENT);
                __hip_atomic_store(&o[1], __float_as_uint(cy), __ATOMIC_RELAXED, __HIP_MEMORY_SCOPE_AGENT);
                __hip_atomic_store(&o[2], __float_as_uint(cz), __ATOMIC_RELAXED, __HIP_MEMORY_SCOPE_AGENT);
                __hip_atomic_store(&prog[b * 16], (unsigned)(step + 1), __ATOMIC_RELEASE, __HIP_MEMORY_SCOPE_AGENT);
            }
        }
    } else {
        // ================= kNN worker branch (r4 body per query) ===========
        const int w2 = (blk - BB) * 8 + wave;       // 0..1919
        const unsigned long long ltmask = (1ull << lane) - 1ull;

        for (int qid = w2; qid < BB * SS; qid += NWORKW) {
            const int b = qid >> 10, s = qid & 1023;

            // wait for centroid s of batch b
            if (lane == 0) {
                int guard = 0;
                while (__hip_atomic_load(&prog[b * 16], __ATOMIC_ACQUIRE,
                                         __HIP_MEMORY_SCOPE_AGENT) < (unsigned)(s + 1) &&
                       ++guard < (1 << 16)) {
                    __builtin_amdgcn_s_sleep(1);
                }
            }
            float qx = 0.0f, qy = 0.0f, qz = 0.0f;
            if (lane == 0) {
                const unsigned* o = (const unsigned*)(new_xyz + (size_t)qid * 3);
                qx = __uint_as_float(__hip_atomic_load(&o[0], __ATOMIC_RELAXED, __HIP_MEMORY_SCOPE_AGENT));
                qy = __uint_as_float(__hip_atomic_load(&o[1], __ATOMIC_RELAXED, __HIP_MEMORY_SCOPE_AGENT));
                qz = __uint_as_float(__hip_atomic_load(&o[2], __ATOMIC_RELAXED, __HIP_MEMORY_SCOPE_AGENT));
            }
            qx = __shfl(qx, 0); qy = __shfl(qy, 0); qz = __shfl(qz, 0);
            float qq = __fadd_rn(__fadd_rn(__fmul_rn(qx, qx), __fmul_rn(qy, qy)), __fmul_rn(qz, qz));

            const float* pb = xyzf + (size_t)b * NN * 3;

            unsigned mk[128];
            unsigned long long lmin = ~0ull;
#pragma unroll
            for (int j = 0; j < 128; j++) {
                int idx = j * 64 + lane;
                float px = pb[idx * 3 + 0];
                float py = pb[idx * 3 + 1];
                float pz = pb[idx * 3 + 2];
                float dot = __fadd_rn(__fadd_rn(__fmul_rn(qx, px), __fmul_rn(qy, py)), __fmul_rn(qz, pz));
                float pp  = __fadd_rn(__fadd_rn(__fmul_rn(px, px), __fmul_rn(py, py)), __fmul_rn(pz, pz));
                float d = __fadd_rn(__fadd_rn(__fmul_rn(-2.0f, dot), qq), pp);
                mk[j] = mkey32(d);
                unsigned long long key = ((unsigned long long)mk[j] << 32) | (unsigned)idx;
                lmin = key < lmin ? key : lmin;
            }

            unsigned long long vs = bitonic64(lmin, lane);
            unsigned long long That = __shfl(vs, 31);

            for (int i = lane; i < BUFC; i += 64) buf[wave][i] = ~0ull;
            int base = 0;
#pragma unroll
            for (int j = 0; j < 128; j++) {
                unsigned long long key = ((unsigned long long)mk[j] << 32) | (unsigned)(j * 64 + lane);
                bool f = key <= That;
                unsigned long long bal = __ballot(f);
                int pos = base + __popcll(bal & ltmask);
                if (f && pos < BUFC) buf[wave][pos] = key;
                base += __popcll(bal);
            }

            if (base > BUFC) {
                unsigned lo = 0, hi = (unsigned)(That >> 32);
                for (int it = 0; it < 32; it++) {
                    unsigned mid = lo + ((hi - lo) >> 1);
                    int c = 0;
#pragma unroll
                    for (int j = 0; j < 128; j++) c += (mk[j] <= mid) ? 1 : 0;
#pragma unroll
                    for (int o = 32; o > 0; o >>= 1) c += __shfl_xor(c, o);
                    if (c >= 32) hi = mid; else lo = mid + 1;
                }
                That = ((unsigned long long)hi << 32) | 0xFFFFFFFFull;
                for (int i = lane; i < BUFC; i += 64) buf[wave][i] = ~0ull;
                base = 0;
#pragma unroll
                for (int j = 0; j < 128; j++) {
                    unsigned long long key = ((unsigned long long)mk[j] << 32) | (unsigned)(j * 64 + lane);
                    bool f = key <= That;
                    unsigned long long bal = __ballot(f);
                    int pos = base + __popcll(bal & ltmask);
                    if (f && pos < BUFC) buf[wave][pos] = key;
                    base += __popcll(bal);
                }
                if (base > BUFC) base = BUFC;
            }

            int M = base;
            unsigned long long kept = ~0ull;
            if (M <= 64) {
                unsigned long long v = (lane < M) ? buf[wave][lane] : ~0ull;
                v = bitonic64(v, lane);
                kept = v;
            } else {
                unsigned long long c0 = buf[wave][lane];
                unsigned long long c1 = buf[wave][64 + lane];
                unsigned long long c2 = buf[wave][128 + lane];
                unsigned long long c3 = buf[wave][192 + lane];
                for (int r = 0; r < KK; r++) {
                    unsigned long long m01 = c0 < c1 ? c0 : c1;
                    unsigned long long m23 = c2 < c3 ? c2 : c3;
                    unsigned long long mm = m01 < m23 ? m01 : m23;
#pragma unroll
                    for (int o = 32; o > 0; o >>= 1) {
                        unsigned long long t2 = __shfl_xor(mm, o);
                        mm = t2 < mm ? t2 : mm;
                    }
                    if (lane == r) kept = mm;
                    c0 = (c0 == mm) ? ~0ull : c0;
                    c1 = (c1 == mm) ? ~0ull : c1;
                    c2 = (c2 == mm) ? ~0ull : c2;
                    c3 = (c3 == mm) ? ~0ull : c3;
                }
            }

            bool act = (lane < KK);
            float gx = 0.0f, gy = 0.0f, gz = 0.0f;
            if (act) {
                unsigned nidx = (unsigned)kept;
                gx = pb[nidx * 3 + 0];
                gy = pb[nidx * 3 + 1];
                gz = pb[nidx * 3 + 2];
            }
            float dx = __fsub_rn(gx, qx);
            float dy = __fsub_rn(gy, qy);
            float dz = __fsub_rn(gz, qz);
            float mx = act ? dx : -3.402823466e38f;
            float my = act ? dy : -3.402823466e38f;
            float mz = act ? dz : -3.402823466e38f;
            float sx = act ? dx : 0.0f;
            float sy = act ? dy : 0.0f;
            float sz = act ? dz : 0.0f;
            double s1 = act ? ((double)dx + (double)dy + (double)dz) : 0.0;
            double s2 = act ? ((double)dx * dx + (double)dy * dy + (double)dz * dz) : 0.0;
#pragma unroll
            for (int o = 32; o > 0; o >>= 1) {
                mx = fmaxf(mx, __shfl_xor(mx, o));
                my = fmaxf(my, __shfl_xor(my, o));
                mz = fmaxf(mz, __shfl_xor(mz, o));
                sx += __shfl_xor(sx, o);
                sy += __shfl_xor(sy, o);
                sz += __shfl_xor(sz, o);
                s1 += __shfl_xor(s1, o);
                s2 += __shfl_xor(s2, o);
            }
            if (lane == 0) {
                float* a = A + ((size_t)b * SS + s) * 3;
                a[0] = __fadd_rn(mx, __fmul_rn(sx, 0.03125f));
                a[1] = __fadd_rn(my, __fmul_rn(sy, 0.03125f));
                a[2] = __fadd_rn(mz, __fmul_rn(sz, 0.03125f));
                qstats[2 * qid + 0] = s1;
                qstats[2 * qid + 1] = s2;
            }
        }
    }
}

// ---------------------------------------------------------------------------
// K2b: reduce per-query stats -> global stats[0..1]. One block.
// ---------------------------------------------------------------------------
__global__ __launch_bounds__(256) void reduce_stats_kernel(const double* __restrict__ qstats,
                                                           double* __restrict__ stats) {
    __shared__ double r1[4], r2[4];
    int t = threadIdx.x;
    double a = 0.0, bsum = 0.0;
    for (int i = t; i < BB * SS; i += 256) { a += qstats[2 * i]; bsum += qstats[2 * i + 1]; }
#pragma unroll
    for (int o = 32; o > 0; o >>= 1) { a += __shfl_xor(a, o); bsum += __shfl_xor(bsum, o); }
    int wv = t >> 6, ln = t & 63;
    if (ln == 0) { r1[wv] = a; r2[wv] = bsum; }
    __syncthreads();
    if (t == 0) {
        stats[0] = r1[0] + r1[1] + r1[2] + r1[3];
        stats[1] = r2[0] + r2[1] + r2[2] + r2[3];
    }
}

// ---------------------------------------------------------------------------
// K3: lc[b,c,s]: c<3 -> A/(std+1e-5); c>=3 -> 2*new_xyz. Accumulate BN1 sums.
// ---------------------------------------------------------------------------
__global__ __launch_bounds__(256) void lc_kernel(const float* __restrict__ new_xyz,
                                                 const float* __restrict__ A,
                                                 const double* __restrict__ stats,
                                                 float* __restrict__ lc,
                                                 double* __restrict__ bn1acc) {
    __shared__ double red[4];
    const int b = blockIdx.x / 6, c = blockIdx.x % 6;
    const int t = threadIdx.x;
    const double n = (double)BB * SS * KK * 3;
    double sd = stats[0], sq = stats[1];
    double var = (sq - sd * sd / n) / (n - 1.0);
    float stdv = (float)sqrt(var);
    float denom = __fadd_rn(stdv, 1e-5f);

    double s1 = 0.0, s2 = 0.0;
    for (int r = 0; r < 4; r++) {
        int s = r * 256 + t;
        float v;
        if (c < 3) {
            v = A[((size_t)b * SS + s) * 3 + c] / denom;
        } else {
            float ww = new_xyz[((size_t)b * SS + s) * 3 + (c - 3)];
            v = __fadd_rn(ww, ww);
        }
        lc[((size_t)b * 6 + c) * SS + s] = v;
        s1 += (double)v;
        s2 += (double)v * (double)v;
    }
#pragma unroll
    for (int off = 32; off > 0; off >>= 1) { s1 += __shfl_down(s1, off); s2 += __shfl_down(s2, off); }
    int wv = t >> 6, ln = t & 63;
    if (ln == 0) red[wv] = s1;
    __syncthreads();
    if (t == 0) atomicAdd(&bn1acc[c * 2 + 0], red[0] + red[1] + red[2] + red[3]);
    __syncthreads();
    if (ln == 0) red[wv] = s2;
    __syncthreads();
    if (t == 0) atomicAdd(&bn1acc[c * 2 + 1], red[0] + red[1] + red[2] + red[3]);
}

// ---------------------------------------------------------------------------
// K4a: per-batch: y = relu(BN1(lc)), then 6x6 safe cdist over S. 16 blocks.
// ---------------------------------------------------------------------------
__global__ __launch_bounds__(256) void cdist_kernel(const float* __restrict__ lc,
                                                    const double* __restrict__ bn1acc,
                                                    const float* __restrict__ params,
                                                    float* __restrict__ tf) {
    __shared__ float sy[6 * SS];
    const int b = blockIdx.x, t = threadIdx.x;
    float mean[6], sde[6], gg[6], bt[6];
    const double n = (double)BB * SS;
#pragma unroll
    for (int c = 0; c < 6; c++) {
        double m = bn1acc[c * 2 + 0] / n;
        double v = bn1acc[c * 2 + 1] / n - m * m;
        mean[c] = (float)m;
        sde[c] = sqrtf((float)v + 1e-5f);
        gg[c] = params[c];
        bt[c] = params[6 + c];
    }
    for (int r = 0; r < 24; r++) {
        int g = r * 256 + t;
        int c = g >> 10;
        float v = lc[(size_t)b * 6 * SS + g];
        float y = (v - mean[c]) / sde[c] * gg[c] + bt[c];
        sy[g] = fmaxf(y, 0.0f);
    }
    __syncthreads();
    if (t < 6) tf[b * 36 + t * 7] = 0.0f;

    const int w = t >> 6, lane = t & 63;
    const int PI[15] = {0,0,0,0,0,1,1,1,1,2,2,2,3,3,4};
    const int PJ[15] = {1,2,3,4,5,2,3,4,5,3,4,5,4,5,5};
    for (int r = 0; r < 4; r++) {
        int p = w + r * 4;
        if (p < 15) {
            int i = PI[p], j = PJ[p];
            float acc = 0.0f;
            for (int m2 = 0; m2 < 16; m2++) {
                int s = lane + m2 * 64;
                float d = sy[i * SS + s] - sy[j * SS + s];
                acc += d * d;
            }
#pragma unroll
            for (int off = 32; off > 0; off >>= 1) acc += __shfl_down(acc, off);
            if (lane == 0) {
                float v = acc > 0.0f ? sqrtf(acc) : 0.0f;
                const float FACTOR = 1.0f;
                tf[b * 36 + i * 6 + j] = (j == i + 1) ? v * FACTOR : v;
                tf[b * 36 + j * 6 + i] = v;
            }
        }
    }
}

// ---------------------------------------------------------------------------
// K4b: BN2 over batch per feature + relu -> out [16,36] (dtype per params[84]).
// ---------------------------------------------------------------------------
__global__ __launch_bounds__(64) void bn2_kernel(const float* __restrict__ tf,
                                                 const float* __restrict__ params,
                                                 void* __restrict__ out_raw) {
    int f = threadIdx.x;
    if (f >= 36) return;
    bool isbf = params[84] != 0.0f;
    float x[16]; float sum = 0.0f;
#pragma unroll
    for (int b = 0; b < 16; b++) { x[b] = tf[b * 36 + f]; sum += x[b]; }
    float mean = sum * 0.0625f;
    float vs = 0.0f;
#pragma unroll
    for (int b = 0; b < 16; b++) { float d = x[b] - mean; vs += d * d; }
    float var = vs * 0.0625f;
    float denom = sqrtf(var + 1e-5f);
    float g = params[12 + f], bb = params[48 + f];
#pragma unroll
    for (int b = 0; b < 16; b++) {
        float y = (x[b] - mean) / denom * g + bb;
        y = fmaxf(y, 0.0f);
        if (isbf) ((__hip_bfloat16*)out_raw)[b * 36 + f] = __float2bfloat16(y);
        else      ((float*)out_raw)[b * 36 + f] = y;
    }
}

// ---------------------------------------------------------------------------
// Workspace layout (bytes):
//   0        : xyzf     float[16*8192*3]   (1572864)
//   1572864  : new_xyz  float[16*1024*3]   (196608)  [published via atomics]
//   1769472  : A        float[16*1024*3]   (196608)
//   1966080  : lc       float[16*6*1024]   (393216)
//   2359296  : tfcw     float[16*36]       (2304)    [first 1KB doubles as
//                                                     prog[] during fused k]
//   2361600  : stats    double[14]
//   2361712  : params   float[85]
//   2362112  : qstats   double[16384*2]    (262144)
// ---------------------------------------------------------------------------
extern "C" void kernel_launch(void* const* d_in, const int* in_sizes, int n_in,
                              void* d_out, int out_size, void* d_ws, size_t ws_size,
                              hipStream_t stream) {
    const void* xyz_raw = d_in[0];
    const void* g1r = d_in[1]; const void* b1r = d_in[2];
    const void* g2r = d_in[3]; const void* b2r = d_in[4];
    {
        const void* six[2] = {nullptr, nullptr}; int n6 = 0;
        const void* t36[2] = {nullptr, nullptr}; int n36 = 0;
        const void* big = nullptr;
        for (int i = 0; i < n_in; i++) {
            if (in_sizes[i] == BB * NN * 3) big = d_in[i];
            else if (in_sizes[i] == 6  && n6  < 2) six[n6++]  = d_in[i];
            else if (in_sizes[i] == 36 && n36 < 2) t36[n36++] = d_in[i];
        }
        if (big && n6 == 2 && n36 == 2) {
            xyz_raw = big; g1r = six[0]; b1r = six[1]; g2r = t36[0]; b2r = t36[1];
        }
    }

    char* ws = (char*)d_ws;
    float* xyzf    = (float*)(ws + 0);
    float* new_xyz = (float*)(ws + 1572864);
    float* A       = (float*)(ws + 1769472);
    float* lc      = (float*)(ws + 1966080);
    float* tf      = (float*)(ws + 2359296);
    double* stats  = (double*)(ws + 2361600);
    double* bn1acc = stats + 2;
    float* params  = (float*)(ws + 2361712);
    double* qstats = (double*)(ws + 2362112);
    unsigned* prog = (unsigned*)tf;   // aliases tf; tf written only later

    hipMemsetAsync(stats, 0, 14 * sizeof(double), stream);
    hipLaunchKernelGGL(convert_kernel, dim3(512), dim3(256), 0, stream,
                       xyz_raw, g1r, b1r, g2r, b2r, xyzf, params, d_out, prog);
    hipLaunchKernelGGL(fps_knn_kernel,      dim3(NBLK), dim3(512), 0, stream,
                       xyzf, new_xyz, prog, A, qstats);
    hipLaunchKernelGGL(reduce_stats_kernel, dim3(1),    dim3(256), 0, stream, qstats, stats);
    hipLaunchKernelGGL(lc_kernel,           dim3(96),   dim3(256), 0, stream, new_xyz, A, stats, lc, bn1acc);
    hipLaunchKernelGGL(cdist_kernel,        dim3(16),   dim3(256), 0, stream, lc, bn1acc, params, tf);
    hipLaunchKernelGGL(bn2_kernel,          dim3(1),    dim3(64),  0, stream, tf, params, d_out);

    (void)in_sizes; (void)n_in; (void)out_size; (void)ws_size;
}

// Round 13
// 2166.434 us; speedup vs baseline: 1.5162x; 1.5162x over previous
//
#include <hip/hip_runtime.h>
#include <hip/hip_bf16.h>

// Problem constants (from reference)
constexpr int BB = 16;     // batches
constexpr int NN = 8192;   // points
constexpr int SS = 1024;   // samples (FPS)
constexpr int KK = 32;     // kNN
constexpr int BUFC = 256;  // per-wave candidate buffer (keys <= That)
constexpr int NBLK = 256;  // fused kernel grid = CU count (1 block/CU via LDS)
constexpr int NWORKW = (NBLK - BB) * 8;   // 1920 knn worker waves

__device__ __forceinline__ float b2f(__hip_bfloat16 h) { return __bfloat162float(h); }

// Monotone map f32 -> u32 (order-preserving, bijective; d is never -0 here).
__device__ __forceinline__ unsigned mkey32(float d) {
    unsigned u = __float_as_uint(d);
    return u ^ (0x80000000u | (unsigned)((int)u >> 31));
}

// DPP lane-move of a u64 (both halves move identically).
template <int CTRL, int RMASK>
__device__ __forceinline__ unsigned long long dppmove_u64(unsigned long long v) {
    int lo = (int)(unsigned)v, hi = (int)(unsigned)(v >> 32);
    int nlo = __builtin_amdgcn_update_dpp(lo, lo, CTRL, RMASK, 0xf, false);
    int nhi = __builtin_amdgcn_update_dpp(hi, hi, CTRL, RMASK, 0xf, false);
    return ((unsigned long long)(unsigned)nhi << 32) | (unsigned)nlo;
}

__device__ __forceinline__ unsigned long long u64max(unsigned long long a,
                                                     unsigned long long b) {
    return a > b ? a : b;
}

// Wave64 max-reduce via DPP. Lane 63 holds the max.
__device__ __forceinline__ unsigned long long wave_max_dpp(unsigned long long k) {
    k = u64max(k, dppmove_u64<0x121, 0xf>(k));  // row_ror:1
    k = u64max(k, dppmove_u64<0x122, 0xf>(k));  // row_ror:2
    k = u64max(k, dppmove_u64<0x124, 0xf>(k));  // row_ror:4
    k = u64max(k, dppmove_u64<0x128, 0xf>(k));  // row_ror:8
    k = u64max(k, dppmove_u64<0x142, 0xa>(k));  // row_bcast:15 -> rows 1,3
    k = u64max(k, dppmove_u64<0x143, 0xc>(k));  // row_bcast:31 -> rows 2,3
    return k;
}

// Cross-lane bitonic sort of 64 u64 keys (ascending); lane i ends with i-th smallest.
__device__ __forceinline__ unsigned long long bitonic64(unsigned long long v, int lane) {
#pragma unroll
    for (int k = 2; k <= 64; k <<= 1) {
#pragma unroll
        for (int j = k >> 1; j > 0; j >>= 1) {
            unsigned long long p = __shfl_xor(v, j);
            bool up = ((lane & k) == 0);
            bool lower = ((lane & j) == 0);
            bool take_min = (up == lower);
            v = take_min ? (p < v ? p : v) : (p > v ? p : v);
        }
    }
    return v;
}

// ---------------------------------------------------------------------------
// K0: dtype detection + upcast to f32 workspace + sentinel fill of d_out.
// (slots[] zeroed by hipMemsetAsync in kernel_launch.)
// ---------------------------------------------------------------------------
__global__ __launch_bounds__(256) void convert_kernel(
    const void* __restrict__ xyz_raw, const void* __restrict__ g1r,
    const void* __restrict__ b1r, const void* __restrict__ g2r,
    const void* __restrict__ b2r, float* __restrict__ xyzf,
    float* __restrict__ params, void* __restrict__ out_raw) {
    const unsigned short* u = (const unsigned short*)xyz_raw;
    unsigned short s = u[2 * (threadIdx.x & 63)];
    int e = (s >> 7) & 0xFF;
    unsigned long long m = __ballot(e >= 100 && e <= 140);
    bool isbf = __popcll(m) > 48;

    const int NT = BB * NN * 3;
    int tid = blockIdx.x * blockDim.x + threadIdx.x;
    int stride = gridDim.x * blockDim.x;
    if (isbf) {
        const __hip_bfloat16* p = (const __hip_bfloat16*)xyz_raw;
        for (int i = tid; i < NT; i += stride) xyzf[i] = b2f(p[i]);
    } else {
        const float* p = (const float*)xyz_raw;
        for (int i = tid; i < NT; i += stride) xyzf[i] = p[i];
    }
    if (blockIdx.x == 0 && threadIdx.x < 85) {
        int t = threadIdx.x;
        if (t == 84) {
            params[84] = isbf ? 1.0f : 0.0f;
        } else {
            const void* src; int off;
            if (t < 6)       { src = g1r; off = t; }
            else if (t < 12) { src = b1r; off = t - 6; }
            else if (t < 48) { src = g2r; off = t - 12; }
            else             { src = b2r; off = t - 48; }
            params[t] = isbf ? b2f(((const __hip_bfloat16*)src)[off])
                             : ((const float*)src)[off];
        }
    }
    if (blockIdx.x == 1 && threadIdx.x < 64) {
        for (int i = threadIdx.x; i < 576; i += 64) {
            if (isbf) ((__hip_bfloat16*)out_raw)[i] = __float2bfloat16(1.0f);
            else      ((float*)out_raw)[i] = 1.0f;
        }
    }
}

// ---------------------------------------------------------------------------
// K1 (FUSED, relaxed-only): FPS (blocks 0..15, r7 body) + persistent kNN
// workers (blocks 16..255) in ONE launch.
//  * r11 LESSON: agent-scope ACQUIRE/RELEASE = cache-wide inv/writeback ->
//    2.16 GB of refetch traffic, 2.6x regression. This round uses RELAXED
//    atomics ONLY (LLC point ops, no cache side effects — r8/r9 evidence).
//  * Protocol: fps publishes ONE self-validating u32 per query:
//    slots[b*1024+s] = 0x80000000 | winner_idx (written once, relaxed).
//    knn pollers relaxed-load their own slot (lane 0, s_sleep backoff),
//    extract idx, and read centroid coords from IMMUTABLE xyzf with plain
//    cached loads — bit-identical to fps's own sxyz[idx] read.
//  * new_xyz written with plain stores (read only by later kernels).
//  * Co-residency: 114.8 KB LDS/block -> 1 block/CU, grid = 256 = CU count.
//  * Bounded poll guard -> hang-free even if assumptions break.
//  * r12 fix: s_sleep takes a CONSTANT immediate -> branch to constant calls.
// ---------------------------------------------------------------------------
__global__ __attribute__((amdgpu_flat_work_group_size(512, 512)))
__attribute__((amdgpu_waves_per_eu(2, 2)))
void fps_knn_kernel(const float* __restrict__ xyzf,
                    float* __restrict__ new_xyz,
                    unsigned* __restrict__ slots,
                    float* __restrict__ A,
                    double* __restrict__ qstats) {
    __shared__ float sxyz[NN * 3];                 // 96 KB (fps branch)
    __shared__ unsigned long long skey[2][8];      // fps branch
    __shared__ unsigned long long buf[8][BUFC];    // 16 KB (knn branch)

    const int blk = blockIdx.x, t = threadIdx.x;
    const int wave = t >> 6, lane = t & 63;

    if (blk < BB) {
        // ================= FPS branch (r7 structure + slot publish) ========
        constexpr int T = 512, P = NN / T;
        const int b = blk;
        const float* xb = xyzf + (size_t)b * NN * 3;

        float px[P], py[P], pz[P], ds[P];
#pragma unroll
        for (int j = 0; j < P; j++) {
            int p = t + j * T;
            px[j] = xb[p * 3 + 0];
            py[j] = xb[p * 3 + 1];
            pz[j] = xb[p * 3 + 2];
            ds[j] = 1e10f;
        }
        for (int i = t; i < NN * 3; i += T) sxyz[i] = xb[i];

        float cx = xb[0], cy = xb[1], cz = xb[2];
        if (t == 0) {
            float* o = new_xyz + (size_t)b * SS * 3;   // plain stores (later kernels)
            o[0] = cx; o[1] = cy; o[2] = cz;
            __hip_atomic_store(&slots[b * SS], 0x80000000u | 0u,
                               __ATOMIC_RELAXED, __HIP_MEMORY_SCOPE_AGENT);
        }
        __syncthreads();   // sxyz visible

        for (int step = 1; step < SS; step++) {
            float bv = -1.0f; int bj = 0;
#pragma unroll
            for (int j = 0; j < P; j++) {
                float dx = __fsub_rn(px[j], cx);
                float dy = __fsub_rn(py[j], cy);
                float dz = __fsub_rn(pz[j], cz);
                float d = __fadd_rn(__fadd_rn(__fmul_rn(dx, dx), __fmul_rn(dy, dy)), __fmul_rn(dz, dz));
                float mm = fminf(ds[j], d);
                ds[j] = mm;
                if (mm > bv) { bv = mm; bj = j; }   // first-max kept (lowest idx)
            }
            unsigned idx = (unsigned)(t + bj * T);
            unsigned long long key =
                ((unsigned long long)__float_as_uint(bv) << 32) | (unsigned)(~idx);

            key = wave_max_dpp(key);
            const int par = step & 1;
            if (lane == 63) skey[par][wave] = key;
            __syncthreads();

            unsigned long long k0 = u64max(skey[par][0], skey[par][1]);
            unsigned long long k1 = u64max(skey[par][2], skey[par][3]);
            unsigned long long k2 = u64max(skey[par][4], skey[par][5]);
            unsigned long long k3 = u64max(skey[par][6], skey[par][7]);
            unsigned long long bk = u64max(u64max(k0, k1), u64max(k2, k3));

            unsigned gidx = ~(unsigned)bk;
            cx = sxyz[gidx * 3 + 0];
            cy = sxyz[gidx * 3 + 1];
            cz = sxyz[gidx * 3 + 2];
            if (t == 0) {
                float* o = new_xyz + ((size_t)b * SS + step) * 3;
                o[0] = cx; o[1] = cy; o[2] = cz;
                __hip_atomic_store(&slots[b * SS + step], 0x80000000u | gidx,
                                   __ATOMIC_RELAXED, __HIP_MEMORY_SCOPE_AGENT);
            }
        }
    } else {
        // ================= kNN worker branch (r4 body per query) ===========
        const int w2 = (blk - BB) * 8 + wave;       // 0..1919
        const unsigned long long ltmask = (1ull << lane) - 1ull;

        for (int qid = w2; qid < BB * SS; qid += NWORKW) {
            const int b = qid >> 10;
            const float* pb = xyzf + (size_t)b * NN * 3;

            // wait for this query's centroid index (relaxed poll, lane 0)
            unsigned v = 0;
            if (lane == 0) {
                v = __hip_atomic_load(&slots[qid], __ATOMIC_RELAXED,
                                      __HIP_MEMORY_SCOPE_AGENT);
                int g = 0;
                while (!(v & 0x80000000u) && ++g < (1 << 20)) {
                    if (g < 8) { __builtin_amdgcn_s_sleep(4); }
                    else       { __builtin_amdgcn_s_sleep(64); }
                    v = __hip_atomic_load(&slots[qid], __ATOMIC_RELAXED,
                                          __HIP_MEMORY_SCOPE_AGENT);
                }
            }
            v = __shfl(v, 0);
            unsigned cidx = v & 8191u;

            float qx = pb[cidx * 3 + 0];    // plain cached loads, same bits
            float qy = pb[cidx * 3 + 1];    // as fps's sxyz[cidx] read
            float qz = pb[cidx * 3 + 2];
            float qq = __fadd_rn(__fadd_rn(__fmul_rn(qx, qx), __fmul_rn(qy, qy)), __fmul_rn(qz, qz));

            unsigned mk[128];
            unsigned long long lmin = ~0ull;
#pragma unroll
            for (int j = 0; j < 128; j++) {
                int idx = j * 64 + lane;
                float px = pb[idx * 3 + 0];
                float py = pb[idx * 3 + 1];
                float pz = pb[idx * 3 + 2];
                float dot = __fadd_rn(__fadd_rn(__fmul_rn(qx, px), __fmul_rn(qy, py)), __fmul_rn(qz, pz));
                float pp  = __fadd_rn(__fadd_rn(__fmul_rn(px, px), __fmul_rn(py, py)), __fmul_rn(pz, pz));
                float d = __fadd_rn(__fadd_rn(__fmul_rn(-2.0f, dot), qq), pp);
                mk[j] = mkey32(d);
                unsigned long long key = ((unsigned long long)mk[j] << 32) | (unsigned)idx;
                lmin = key < lmin ? key : lmin;
            }

            unsigned long long vs = bitonic64(lmin, lane);
            unsigned long long That = __shfl(vs, 31);

            for (int i = lane; i < BUFC; i += 64) buf[wave][i] = ~0ull;
            int base = 0;
#pragma unroll
            for (int j = 0; j < 128; j++) {
                unsigned long long key = ((unsigned long long)mk[j] << 32) | (unsigned)(j * 64 + lane);
                bool f = key <= That;
                unsigned long long bal = __ballot(f);
                int pos = base + __popcll(bal & ltmask);
                if (f && pos < BUFC) buf[wave][pos] = key;
                base += __popcll(bal);
            }

            if (base > BUFC) {
                unsigned lo = 0, hi = (unsigned)(That >> 32);
                for (int it = 0; it < 32; it++) {
                    unsigned mid = lo + ((hi - lo) >> 1);
                    int c = 0;
#pragma unroll
                    for (int j = 0; j < 128; j++) c += (mk[j] <= mid) ? 1 : 0;
#pragma unroll
                    for (int o = 32; o > 0; o >>= 1) c += __shfl_xor(c, o);
                    if (c >= 32) hi = mid; else lo = mid + 1;
                }
                That = ((unsigned long long)hi << 32) | 0xFFFFFFFFull;
                for (int i = lane; i < BUFC; i += 64) buf[wave][i] = ~0ull;
                base = 0;
#pragma unroll
                for (int j = 0; j < 128; j++) {
                    unsigned long long key = ((unsigned long long)mk[j] << 32) | (unsigned)(j * 64 + lane);
                    bool f = key <= That;
                    unsigned long long bal = __ballot(f);
                    int pos = base + __popcll(bal & ltmask);
                    if (f && pos < BUFC) buf[wave][pos] = key;
                    base += __popcll(bal);
                }
                if (base > BUFC) base = BUFC;
            }

            int M = base;
            unsigned long long kept = ~0ull;
            if (M <= 64) {
                unsigned long long vv = (lane < M) ? buf[wave][lane] : ~0ull;
                vv = bitonic64(vv, lane);
                kept = vv;
            } else {
                unsigned long long c0 = buf[wave][lane];
                unsigned long long c1 = buf[wave][64 + lane];
                unsigned long long c2 = buf[wave][128 + lane];
                unsigned long long c3 = buf[wave][192 + lane];
                for (int r = 0; r < KK; r++) {
                    unsigned long long m01 = c0 < c1 ? c0 : c1;
                    unsigned long long m23 = c2 < c3 ? c2 : c3;
                    unsigned long long mm = m01 < m23 ? m01 : m23;
#pragma unroll
                    for (int o = 32; o > 0; o >>= 1) {
                        unsigned long long t2 = __shfl_xor(mm, o);
                        mm = t2 < mm ? t2 : mm;
                    }
                    if (lane == r) kept = mm;
                    c0 = (c0 == mm) ? ~0ull : c0;
                    c1 = (c1 == mm) ? ~0ull : c1;
                    c2 = (c2 == mm) ? ~0ull : c2;
                    c3 = (c3 == mm) ? ~0ull : c3;
                }
            }

            bool act = (lane < KK);
            float gx = 0.0f, gy = 0.0f, gz = 0.0f;
            if (act) {
                unsigned nidx = (unsigned)kept;
                gx = pb[nidx * 3 + 0];
                gy = pb[nidx * 3 + 1];
                gz = pb[nidx * 3 + 2];
            }
            float dx = __fsub_rn(gx, qx);
            float dy = __fsub_rn(gy, qy);
            float dz = __fsub_rn(gz, qz);
            float mx = act ? dx : -3.402823466e38f;
            float my = act ? dy : -3.402823466e38f;
            float mz = act ? dz : -3.402823466e38f;
            float sx = act ? dx : 0.0f;
            float sy = act ? dy : 0.0f;
            float sz = act ? dz : 0.0f;
            double s1 = act ? ((double)dx + (double)dy + (double)dz) : 0.0;
            double s2 = act ? ((double)dx * dx + (double)dy * dy + (double)dz * dz) : 0.0;
#pragma unroll
            for (int o = 32; o > 0; o >>= 1) {
                mx = fmaxf(mx, __shfl_xor(mx, o));
                my = fmaxf(my, __shfl_xor(my, o));
                mz = fmaxf(mz, __shfl_xor(mz, o));
                sx += __shfl_xor(sx, o);
                sy += __shfl_xor(sy, o);
                sz += __shfl_xor(sz, o);
                s1 += __shfl_xor(s1, o);
                s2 += __shfl_xor(s2, o);
            }
            if (lane == 0) {
                float* a = A + (size_t)qid * 3;
                a[0] = __fadd_rn(mx, __fmul_rn(sx, 0.03125f));
                a[1] = __fadd_rn(my, __fmul_rn(sy, 0.03125f));
                a[2] = __fadd_rn(mz, __fmul_rn(sz, 0.03125f));
                qstats[2 * qid + 0] = s1;
                qstats[2 * qid + 1] = s2;
            }
        }
    }
}

// ---------------------------------------------------------------------------
// K2b: reduce per-query stats -> global stats[0..1]. One block.
// ---------------------------------------------------------------------------
__global__ __launch_bounds__(256) void reduce_stats_kernel(const double* __restrict__ qstats,
                                                           double* __restrict__ stats) {
    __shared__ double r1[4], r2[4];
    int t = threadIdx.x;
    double a = 0.0, bsum = 0.0;
    for (int i = t; i < BB * SS; i += 256) { a += qstats[2 * i]; bsum += qstats[2 * i + 1]; }
#pragma unroll
    for (int o = 32; o > 0; o >>= 1) { a += __shfl_xor(a, o); bsum += __shfl_xor(bsum, o); }
    int wv = t >> 6, ln = t & 63;
    if (ln == 0) { r1[wv] = a; r2[wv] = bsum; }
    __syncthreads();
    if (t == 0) {
        stats[0] = r1[0] + r1[1] + r1[2] + r1[3];
        stats[1] = r2[0] + r2[1] + r2[2] + r2[3];
    }
}

// ---------------------------------------------------------------------------
// K3: lc[b,c,s]: c<3 -> A/(std+1e-5); c>=3 -> 2*new_xyz. Accumulate BN1 sums.
// ---------------------------------------------------------------------------
__global__ __launch_bounds__(256) void lc_kernel(const float* __restrict__ new_xyz,
                                                 const float* __restrict__ A,
                                                 const double* __restrict__ stats,
                                                 float* __restrict__ lc,
                                                 double* __restrict__ bn1acc) {
    __shared__ double red[4];
    const int b = blockIdx.x / 6, c = blockIdx.x % 6;
    const int t = threadIdx.x;
    const double n = (double)BB * SS * KK * 3;
    double sd = stats[0], sq = stats[1];
    double var = (sq - sd * sd / n) / (n - 1.0);
    float stdv = (float)sqrt(var);
    float denom = __fadd_rn(stdv, 1e-5f);

    double s1 = 0.0, s2 = 0.0;
    for (int r = 0; r < 4; r++) {
        int s = r * 256 + t;
        float v;
        if (c < 3) {
            v = A[((size_t)b * SS + s) * 3 + c] / denom;
        } else {
            float ww = new_xyz[((size_t)b * SS + s) * 3 + (c - 3)];
            v = __fadd_rn(ww, ww);
        }
        lc[((size_t)b * 6 + c) * SS + s] = v;
        s1 += (double)v;
        s2 += (double)v * (double)v;
    }
#pragma unroll
    for (int off = 32; off > 0; off >>= 1) { s1 += __shfl_down(s1, off); s2 += __shfl_down(s2, off); }
    int wv = t >> 6, ln = t & 63;
    if (ln == 0) red[wv] = s1;
    __syncthreads();
    if (t == 0) atomicAdd(&bn1acc[c * 2 + 0], red[0] + red[1] + red[2] + red[3]);
    __syncthreads();
    if (ln == 0) red[wv] = s2;
    __syncthreads();
    if (t == 0) atomicAdd(&bn1acc[c * 2 + 1], red[0] + red[1] + red[2] + red[3]);
}

// ---------------------------------------------------------------------------
// K4a: per-batch: y = relu(BN1(lc)), then 6x6 safe cdist over S. 16 blocks.
// ---------------------------------------------------------------------------
__global__ __launch_bounds__(256) void cdist_kernel(const float* __restrict__ lc,
                                                    const double* __restrict__ bn1acc,
                                                    const float* __restrict__ params,
                                                    float* __restrict__ tf) {
    __shared__ float sy[6 * SS];
    const int b = blockIdx.x, t = threadIdx.x;
    float mean[6], sde[6], gg[6], bt[6];
    const double n = (double)BB * SS;
#pragma unroll
    for (int c = 0; c < 6; c++) {
        double m = bn1acc[c * 2 + 0] / n;
        double v = bn1acc[c * 2 + 1] / n - m * m;
        mean[c] = (float)m;
        sde[c] = sqrtf((float)v + 1e-5f);
        gg[c] = params[c];
        bt[c] = params[6 + c];
    }
    for (int r = 0; r < 24; r++) {
        int g = r * 256 + t;
        int c = g >> 10;
        float v = lc[(size_t)b * 6 * SS + g];
        float y = (v - mean[c]) / sde[c] * gg[c] + bt[c];
        sy[g] = fmaxf(y, 0.0f);
    }
    __syncthreads();
    if (t < 6) tf[b * 36 + t * 7] = 0.0f;

    const int w = t >> 6, lane = t & 63;
    const int PI[15] = {0,0,0,0,0,1,1,1,1,2,2,2,3,3,4};
    const int PJ[15] = {1,2,3,4,5,2,3,4,5,3,4,5,4,5,5};
    for (int r = 0; r < 4; r++) {
        int p = w + r * 4;
        if (p < 15) {
            int i = PI[p], j = PJ[p];
            float acc = 0.0f;
            for (int m2 = 0; m2 < 16; m2++) {
                int s = lane + m2 * 64;
                float d = sy[i * SS + s] - sy[j * SS + s];
                acc += d * d;
            }
#pragma unroll
            for (int off = 32; off > 0; off >>= 1) acc += __shfl_down(acc, off);
            if (lane == 0) {
                float v = acc > 0.0f ? sqrtf(acc) : 0.0f;
                const float FACTOR = 1.0f;
                tf[b * 36 + i * 6 + j] = (j == i + 1) ? v * FACTOR : v;
                tf[b * 36 + j * 6 + i] = v;
            }
        }
    }
}

// ---------------------------------------------------------------------------
// K4b: BN2 over batch per feature + relu -> out [16,36] (dtype per params[84]).
// ---------------------------------------------------------------------------
__global__ __launch_bounds__(64) void bn2_kernel(const float* __restrict__ tf,
                                                 const float* __restrict__ params,
                                                 void* __restrict__ out_raw) {
    int f = threadIdx.x;
    if (f >= 36) return;
    bool isbf = params[84] != 0.0f;
    float x[16]; float sum = 0.0f;
#pragma unroll
    for (int b = 0; b < 16; b++) { x[b] = tf[b * 36 + f]; sum += x[b]; }
    float mean = sum * 0.0625f;
    float vs = 0.0f;
#pragma unroll
    for (int b = 0; b < 16; b++) { float d = x[b] - mean; vs += d * d; }
    float var = vs * 0.0625f;
    float denom = sqrtf(var + 1e-5f);
    float g = params[12 + f], bb = params[48 + f];
#pragma unroll
    for (int b = 0; b < 16; b++) {
        float y = (x[b] - mean) / denom * g + bb;
        y = fmaxf(y, 0.0f);
        if (isbf) ((__hip_bfloat16*)out_raw)[b * 36 + f] = __float2bfloat16(y);
        else      ((float*)out_raw)[b * 36 + f] = y;
    }
}

// ---------------------------------------------------------------------------
// Workspace layout (bytes):
//   0        : xyzf     float[16*8192*3]   (1572864)
//   1572864  : new_xyz  float[16*1024*3]   (196608)
//   1769472  : A        float[16*1024*3]   (196608)
//   1966080  : lc       float[16*6*1024]   (393216)
//   2359296  : tfcw     float[16*36]       (2304)
//   2361600  : stats    double[14]
//   2361712  : params   float[85]
//   2362112  : qstats   double[16384*2]    (262144)
//   2624256  : slots    u32[16384]         (65536)  [fps->knn handshake]
// ---------------------------------------------------------------------------
extern "C" void kernel_launch(void* const* d_in, const int* in_sizes, int n_in,
                              void* d_out, int out_size, void* d_ws, size_t ws_size,
                              hipStream_t stream) {
    const void* xyz_raw = d_in[0];
    const void* g1r = d_in[1]; const void* b1r = d_in[2];
    const void* g2r = d_in[3]; const void* b2r = d_in[4];
    {
        const void* six[2] = {nullptr, nullptr}; int n6 = 0;
        const void* t36[2] = {nullptr, nullptr}; int n36 = 0;
        const void* big = nullptr;
        for (int i = 0; i < n_in; i++) {
            if (in_sizes[i] == BB * NN * 3) big = d_in[i];
            else if (in_sizes[i] == 6  && n6  < 2) six[n6++]  = d_in[i];
            else if (in_sizes[i] == 36 && n36 < 2) t36[n36++] = d_in[i];
        }
        if (big && n6 == 2 && n36 == 2) {
            xyz_raw = big; g1r = six[0]; b1r = six[1]; g2r = t36[0]; b2r = t36[1];
        }
    }

    char* ws = (char*)d_ws;
    float* xyzf    = (float*)(ws + 0);
    float* new_xyz = (float*)(ws + 1572864);
    float* A       = (float*)(ws + 1769472);
    float* lc      = (float*)(ws + 1966080);
    float* tf      = (float*)(ws + 2359296);
    double* stats  = (double*)(ws + 2361600);
    double* bn1acc = stats + 2;
    float* params  = (float*)(ws + 2361712);
    double* qstats = (double*)(ws + 2362112);
    unsigned* slots = (unsigned*)(ws + 2624256);

    hipMemsetAsync(stats, 0, 14 * sizeof(double), stream);
    hipMemsetAsync(slots, 0, BB * SS * sizeof(unsigned), stream);
    hipLaunchKernelGGL(convert_kernel, dim3(512), dim3(256), 0, stream,
                       xyz_raw, g1r, b1r, g2r, b2r, xyzf, params, d_out);
    hipLaunchKernelGGL(fps_knn_kernel,      dim3(NBLK), dim3(512), 0, stream,
                       xyzf, new_xyz, slots, A, qstats);
    hipLaunchKernelGGL(reduce_stats_kernel, dim3(1),    dim3(256), 0, stream, qstats, stats);
    hipLaunchKernelGGL(lc_kernel,           dim3(96),   dim3(256), 0, stream, new_xyz, A, stats, lc, bn1acc);
    hipLaunchKernelGGL(cdist_kernel,        dim3(16),   dim3(256), 0, stream, lc, bn1acc, params, tf);
    hipLaunchKernelGGL(bn2_kernel,          dim3(1),    dim3(64),  0, stream, tf, params, d_out);

    (void)in_sizes; (void)n_in; (void)out_size; (void)ws_size;
}

// Round 14
// 1394.183 us; speedup vs baseline: 2.3560x; 1.5539x over previous
//
#include <hip/hip_runtime.h>
#include <hip/hip_bf16.h>

// Problem constants (from reference)
constexpr int BB = 16;     // batches
constexpr int NN = 8192;   // points
constexpr int SS = 1024;   // samples (FPS)
constexpr int KK = 32;     // kNN
constexpr int BUFC = 256;  // per-wave candidate buffer (keys <= That)
constexpr int NBLK = 256;  // fused kernel grid = CU count (1 block/CU via LDS)
constexpr int NWORKW = (NBLK - BB) * 8;   // 1920 knn worker waves

__device__ __forceinline__ float b2f(__hip_bfloat16 h) { return __bfloat162float(h); }

// Monotone map f32 -> u32 (order-preserving, bijective; d is never -0 here).
__device__ __forceinline__ unsigned mkey32(float d) {
    unsigned u = __float_as_uint(d);
    return u ^ (0x80000000u | (unsigned)((int)u >> 31));
}

// Deterministic distance key for point idx vs query (qx,qy,qz,qq).
// Same expression sequence every call -> bit-identical results (IEEE, no FMA).
__device__ __forceinline__ unsigned long long dist_key(const float* __restrict__ pb,
                                                       int idx, float qx, float qy,
                                                       float qz, float qq) {
    float px = pb[idx * 3 + 0];
    float py = pb[idx * 3 + 1];
    float pz = pb[idx * 3 + 2];
    float dot = __fadd_rn(__fadd_rn(__fmul_rn(qx, px), __fmul_rn(qy, py)), __fmul_rn(qz, pz));
    float pp  = __fadd_rn(__fadd_rn(__fmul_rn(px, px), __fmul_rn(py, py)), __fmul_rn(pz, pz));
    float d = __fadd_rn(__fadd_rn(__fmul_rn(-2.0f, dot), qq), pp);
    return ((unsigned long long)mkey32(d) << 32) | (unsigned)idx;
}

// DPP lane-move of a u64 (both halves move identically).
template <int CTRL, int RMASK>
__device__ __forceinline__ unsigned long long dppmove_u64(unsigned long long v) {
    int lo = (int)(unsigned)v, hi = (int)(unsigned)(v >> 32);
    int nlo = __builtin_amdgcn_update_dpp(lo, lo, CTRL, RMASK, 0xf, false);
    int nhi = __builtin_amdgcn_update_dpp(hi, hi, CTRL, RMASK, 0xf, false);
    return ((unsigned long long)(unsigned)nhi << 32) | (unsigned)nlo;
}

__device__ __forceinline__ unsigned long long u64max(unsigned long long a,
                                                     unsigned long long b) {
    return a > b ? a : b;
}

// Wave64 max-reduce via DPP. Lane 63 holds the max.
__device__ __forceinline__ unsigned long long wave_max_dpp(unsigned long long k) {
    k = u64max(k, dppmove_u64<0x121, 0xf>(k));  // row_ror:1
    k = u64max(k, dppmove_u64<0x122, 0xf>(k));  // row_ror:2
    k = u64max(k, dppmove_u64<0x124, 0xf>(k));  // row_ror:4
    k = u64max(k, dppmove_u64<0x128, 0xf>(k));  // row_ror:8
    k = u64max(k, dppmove_u64<0x142, 0xa>(k));  // row_bcast:15 -> rows 1,3
    k = u64max(k, dppmove_u64<0x143, 0xc>(k));  // row_bcast:31 -> rows 2,3
    return k;
}

// Cross-lane bitonic sort of 64 u64 keys (ascending); lane i ends with i-th smallest.
__device__ __forceinline__ unsigned long long bitonic64(unsigned long long v, int lane) {
#pragma unroll
    for (int k = 2; k <= 64; k <<= 1) {
#pragma unroll
        for (int j = k >> 1; j > 0; j >>= 1) {
            unsigned long long p = __shfl_xor(v, j);
            bool up = ((lane & k) == 0);
            bool lower = ((lane & j) == 0);
            bool take_min = (up == lower);
            v = take_min ? (p < v ? p : v) : (p > v ? p : v);
        }
    }
    return v;
}

// ---------------------------------------------------------------------------
// K0: dtype detection + upcast to f32 workspace + sentinel fill of d_out.
// (slots[] zeroed by hipMemsetAsync in kernel_launch.)
// ---------------------------------------------------------------------------
__global__ __launch_bounds__(256) void convert_kernel(
    const void* __restrict__ xyz_raw, const void* __restrict__ g1r,
    const void* __restrict__ b1r, const void* __restrict__ g2r,
    const void* __restrict__ b2r, float* __restrict__ xyzf,
    float* __restrict__ params, void* __restrict__ out_raw) {
    const unsigned short* u = (const unsigned short*)xyz_raw;
    unsigned short s = u[2 * (threadIdx.x & 63)];
    int e = (s >> 7) & 0xFF;
    unsigned long long m = __ballot(e >= 100 && e <= 140);
    bool isbf = __popcll(m) > 48;

    const int NT = BB * NN * 3;
    int tid = blockIdx.x * blockDim.x + threadIdx.x;
    int stride = gridDim.x * blockDim.x;
    if (isbf) {
        const __hip_bfloat16* p = (const __hip_bfloat16*)xyz_raw;
        for (int i = tid; i < NT; i += stride) xyzf[i] = b2f(p[i]);
    } else {
        const float* p = (const float*)xyz_raw;
        for (int i = tid; i < NT; i += stride) xyzf[i] = p[i];
    }
    if (blockIdx.x == 0 && threadIdx.x < 85) {
        int t = threadIdx.x;
        if (t == 84) {
            params[84] = isbf ? 1.0f : 0.0f;
        } else {
            const void* src; int off;
            if (t < 6)       { src = g1r; off = t; }
            else if (t < 12) { src = b1r; off = t - 6; }
            else if (t < 48) { src = g2r; off = t - 12; }
            else             { src = b2r; off = t - 48; }
            params[t] = isbf ? b2f(((const __hip_bfloat16*)src)[off])
                             : ((const float*)src)[off];
        }
    }
    if (blockIdx.x == 1 && threadIdx.x < 64) {
        for (int i = threadIdx.x; i < 576; i += 64) {
            if (isbf) ((__hip_bfloat16*)out_raw)[i] = __float2bfloat16(1.0f);
            else      ((float*)out_raw)[i] = 1.0f;
        }
    }
}

// ---------------------------------------------------------------------------
// K1 (FUSED, recompute-knn): FPS (blocks 0..15, r7 body) + persistent kNN
// workers (blocks 16..255) in ONE launch.
//  * r13 LESSON: the 2.2 GB HBM traffic (both r11 AND r13) was the knn
//    mk[128] array SPILLED TO SCRATCH (32 KB/query written+read), not fence
//    refetch. Fix: store nothing — pass 1 tracks only the lane-min key;
//    pass 2 RECOMPUTES each key for the compaction test. IEEE ops on
//    immutable inputs -> bit-identical keys -> selection unchanged.
//  * Relaxed-only handshake kept (r11: acquire/release = cache-wide
//    inv/wb, halves achieved BW).
//  * Co-residency: 114.8 KB LDS/block -> 1 block/CU, grid = 256 = CU count.
//  * Bounded poll guard -> hang-free. s_sleep needs CONSTANT immediates.
// ---------------------------------------------------------------------------
__global__ __attribute__((amdgpu_flat_work_group_size(512, 512)))
__attribute__((amdgpu_waves_per_eu(2, 2)))
void fps_knn_kernel(const float* __restrict__ xyzf,
                    float* __restrict__ new_xyz,
                    unsigned* __restrict__ slots,
                    float* __restrict__ A,
                    double* __restrict__ qstats) {
    __shared__ float sxyz[NN * 3];                 // 96 KB (fps branch)
    __shared__ unsigned long long skey[2][8];      // fps branch
    __shared__ unsigned long long buf[8][BUFC];    // 16 KB (knn branch)

    const int blk = blockIdx.x, t = threadIdx.x;
    const int wave = t >> 6, lane = t & 63;

    if (blk < BB) {
        // ================= FPS branch (r7 structure + slot publish) ========
        constexpr int T = 512, P = NN / T;
        const int b = blk;
        const float* xb = xyzf + (size_t)b * NN * 3;

        float px[P], py[P], pz[P], ds[P];
#pragma unroll
        for (int j = 0; j < P; j++) {
            int p = t + j * T;
            px[j] = xb[p * 3 + 0];
            py[j] = xb[p * 3 + 1];
            pz[j] = xb[p * 3 + 2];
            ds[j] = 1e10f;
        }
        for (int i = t; i < NN * 3; i += T) sxyz[i] = xb[i];

        float cx = xb[0], cy = xb[1], cz = xb[2];
        if (t == 0) {
            float* o = new_xyz + (size_t)b * SS * 3;   // plain stores (later kernels)
            o[0] = cx; o[1] = cy; o[2] = cz;
            __hip_atomic_store(&slots[b * SS], 0x80000000u | 0u,
                               __ATOMIC_RELAXED, __HIP_MEMORY_SCOPE_AGENT);
        }
        __syncthreads();   // sxyz visible

        for (int step = 1; step < SS; step++) {
            float bv = -1.0f; int bj = 0;
#pragma unroll
            for (int j = 0; j < P; j++) {
                float dx = __fsub_rn(px[j], cx);
                float dy = __fsub_rn(py[j], cy);
                float dz = __fsub_rn(pz[j], cz);
                float d = __fadd_rn(__fadd_rn(__fmul_rn(dx, dx), __fmul_rn(dy, dy)), __fmul_rn(dz, dz));
                float mm = fminf(ds[j], d);
                ds[j] = mm;
                if (mm > bv) { bv = mm; bj = j; }   // first-max kept (lowest idx)
            }
            unsigned idx = (unsigned)(t + bj * T);
            unsigned long long key =
                ((unsigned long long)__float_as_uint(bv) << 32) | (unsigned)(~idx);

            key = wave_max_dpp(key);
            const int par = step & 1;
            if (lane == 63) skey[par][wave] = key;
            __syncthreads();

            unsigned long long k0 = u64max(skey[par][0], skey[par][1]);
            unsigned long long k1 = u64max(skey[par][2], skey[par][3]);
            unsigned long long k2 = u64max(skey[par][4], skey[par][5]);
            unsigned long long k3 = u64max(skey[par][6], skey[par][7]);
            unsigned long long bk = u64max(u64max(k0, k1), u64max(k2, k3));

            unsigned gidx = ~(unsigned)bk;
            cx = sxyz[gidx * 3 + 0];
            cy = sxyz[gidx * 3 + 1];
            cz = sxyz[gidx * 3 + 2];
            if (t == 0) {
                float* o = new_xyz + ((size_t)b * SS + step) * 3;
                o[0] = cx; o[1] = cy; o[2] = cz;
                __hip_atomic_store(&slots[b * SS + step], 0x80000000u | gidx,
                                   __ATOMIC_RELAXED, __HIP_MEMORY_SCOPE_AGENT);
            }
        }
    } else {
        // ========== kNN worker branch (recompute, no per-lane array) =======
        const int w2 = (blk - BB) * 8 + wave;       // 0..1919
        const unsigned long long ltmask = (1ull << lane) - 1ull;

        for (int qid = w2; qid < BB * SS; qid += NWORKW) {
            const int b = qid >> 10;
            const float* pb = xyzf + (size_t)b * NN * 3;

            // wait for this query's centroid index (relaxed poll, lane 0)
            unsigned v = 0;
            if (lane == 0) {
                v = __hip_atomic_load(&slots[qid], __ATOMIC_RELAXED,
                                      __HIP_MEMORY_SCOPE_AGENT);
                int g = 0;
                while (!(v & 0x80000000u) && ++g < (1 << 20)) {
                    if (g < 8) { __builtin_amdgcn_s_sleep(4); }
                    else       { __builtin_amdgcn_s_sleep(64); }
                    v = __hip_atomic_load(&slots[qid], __ATOMIC_RELAXED,
                                          __HIP_MEMORY_SCOPE_AGENT);
                }
            }
            v = __shfl(v, 0);
            unsigned cidx = v & 8191u;

            float qx = pb[cidx * 3 + 0];    // plain cached loads, same bits
            float qy = pb[cidx * 3 + 1];    // as fps's sxyz[cidx] read
            float qz = pb[cidx * 3 + 2];
            float qq = __fadd_rn(__fadd_rn(__fmul_rn(qx, qx), __fmul_rn(qy, qy)), __fmul_rn(qz, qz));

            // pass 1: lane-min key only (no storage)
            unsigned long long lmin = ~0ull;
            for (int j = 0; j < 128; j++) {
                unsigned long long key = dist_key(pb, j * 64 + lane, qx, qy, qz, qq);
                lmin = key < lmin ? key : lmin;
            }

            unsigned long long vs = bitonic64(lmin, lane);
            unsigned long long That = __shfl(vs, 31);

            // pass 2: recompute keys, compact keys <= That into LDS
            for (int i = lane; i < BUFC; i += 64) buf[wave][i] = ~0ull;
            int base = 0;
            for (int j = 0; j < 128; j++) {
                unsigned long long key = dist_key(pb, j * 64 + lane, qx, qy, qz, qq);
                bool f = key <= That;
                unsigned long long bal = __ballot(f);
                int pos = base + __popcll(bal & ltmask);
                if (f && pos < BUFC) buf[wave][pos] = key;
                base += __popcll(bal);
            }

            // rare recovery: tighten threshold (recompute inside search)
            if (base > BUFC) {
                unsigned lo = 0, hi = (unsigned)(That >> 32);
                for (int it = 0; it < 32; it++) {
                    unsigned mid = lo + ((hi - lo) >> 1);
                    int c = 0;
                    for (int j = 0; j < 128; j++) {
                        unsigned long long key = dist_key(pb, j * 64 + lane, qx, qy, qz, qq);
                        c += ((unsigned)(key >> 32) <= mid) ? 1 : 0;
                    }
#pragma unroll
                    for (int o = 32; o > 0; o >>= 1) c += __shfl_xor(c, o);
                    if (c >= 32) hi = mid; else lo = mid + 1;
                }
                That = ((unsigned long long)hi << 32) | 0xFFFFFFFFull;
                for (int i = lane; i < BUFC; i += 64) buf[wave][i] = ~0ull;
                base = 0;
                for (int j = 0; j < 128; j++) {
                    unsigned long long key = dist_key(pb, j * 64 + lane, qx, qy, qz, qq);
                    bool f = key <= That;
                    unsigned long long bal = __ballot(f);
                    int pos = base + __popcll(bal & ltmask);
                    if (f && pos < BUFC) buf[wave][pos] = key;
                    base += __popcll(bal);
                }
                if (base > BUFC) base = BUFC;
            }

            int M = base;
            unsigned long long kept = ~0ull;
            if (M <= 64) {
                unsigned long long vv = (lane < M) ? buf[wave][lane] : ~0ull;
                vv = bitonic64(vv, lane);
                kept = vv;
            } else {
                unsigned long long c0 = buf[wave][lane];
                unsigned long long c1 = buf[wave][64 + lane];
                unsigned long long c2 = buf[wave][128 + lane];
                unsigned long long c3 = buf[wave][192 + lane];
                for (int r = 0; r < KK; r++) {
                    unsigned long long m01 = c0 < c1 ? c0 : c1;
                    unsigned long long m23 = c2 < c3 ? c2 : c3;
                    unsigned long long mm = m01 < m23 ? m01 : m23;
#pragma unroll
                    for (int o = 32; o > 0; o >>= 1) {
                        unsigned long long t2 = __shfl_xor(mm, o);
                        mm = t2 < mm ? t2 : mm;
                    }
                    if (lane == r) kept = mm;
                    c0 = (c0 == mm) ? ~0ull : c0;
                    c1 = (c1 == mm) ? ~0ull : c1;
                    c2 = (c2 == mm) ? ~0ull : c2;
                    c3 = (c3 == mm) ? ~0ull : c3;
                }
            }

            bool act = (lane < KK);
            float gx = 0.0f, gy = 0.0f, gz = 0.0f;
            if (act) {
                unsigned nidx = (unsigned)kept;
                gx = pb[nidx * 3 + 0];
                gy = pb[nidx * 3 + 1];
                gz = pb[nidx * 3 + 2];
            }
            float dx = __fsub_rn(gx, qx);
            float dy = __fsub_rn(gy, qy);
            float dz = __fsub_rn(gz, qz);
            float mx = act ? dx : -3.402823466e38f;
            float my = act ? dy : -3.402823466e38f;
            float mz = act ? dz : -3.402823466e38f;
            float sx = act ? dx : 0.0f;
            float sy = act ? dy : 0.0f;
            float sz = act ? dz : 0.0f;
            double s1 = act ? ((double)dx + (double)dy + (double)dz) : 0.0;
            double s2 = act ? ((double)dx * dx + (double)dy * dy + (double)dz * dz) : 0.0;
#pragma unroll
            for (int o = 32; o > 0; o >>= 1) {
                mx = fmaxf(mx, __shfl_xor(mx, o));
                my = fmaxf(my, __shfl_xor(my, o));
                mz = fmaxf(mz, __shfl_xor(mz, o));
                sx += __shfl_xor(sx, o);
                sy += __shfl_xor(sy, o);
                sz += __shfl_xor(sz, o);
                s1 += __shfl_xor(s1, o);
                s2 += __shfl_xor(s2, o);
            }
            if (lane == 0) {
                float* a = A + (size_t)qid * 3;
                a[0] = __fadd_rn(mx, __fmul_rn(sx, 0.03125f));
                a[1] = __fadd_rn(my, __fmul_rn(sy, 0.03125f));
                a[2] = __fadd_rn(mz, __fmul_rn(sz, 0.03125f));
                qstats[2 * qid + 0] = s1;
                qstats[2 * qid + 1] = s2;
            }
        }
    }
}

// ---------------------------------------------------------------------------
// K2b: reduce per-query stats -> global stats[0..1]. One block.
// ---------------------------------------------------------------------------
__global__ __launch_bounds__(256) void reduce_stats_kernel(const double* __restrict__ qstats,
                                                           double* __restrict__ stats) {
    __shared__ double r1[4], r2[4];
    int t = threadIdx.x;
    double a = 0.0, bsum = 0.0;
    for (int i = t; i < BB * SS; i += 256) { a += qstats[2 * i]; bsum += qstats[2 * i + 1]; }
#pragma unroll
    for (int o = 32; o > 0; o >>= 1) { a += __shfl_xor(a, o); bsum += __shfl_xor(bsum, o); }
    int wv = t >> 6, ln = t & 63;
    if (ln == 0) { r1[wv] = a; r2[wv] = bsum; }
    __syncthreads();
    if (t == 0) {
        stats[0] = r1[0] + r1[1] + r1[2] + r1[3];
        stats[1] = r2[0] + r2[1] + r2[2] + r2[3];
    }
}

// ---------------------------------------------------------------------------
// K3: lc[b,c,s]: c<3 -> A/(std+1e-5); c>=3 -> 2*new_xyz. Accumulate BN1 sums.
// ---------------------------------------------------------------------------
__global__ __launch_bounds__(256) void lc_kernel(const float* __restrict__ new_xyz,
                                                 const float* __restrict__ A,
                                                 const double* __restrict__ stats,
                                                 float* __restrict__ lc,
                                                 double* __restrict__ bn1acc) {
    __shared__ double red[4];
    const int b = blockIdx.x / 6, c = blockIdx.x % 6;
    const int t = threadIdx.x;
    const double n = (double)BB * SS * KK * 3;
    double sd = stats[0], sq = stats[1];
    double var = (sq - sd * sd / n) / (n - 1.0);
    float stdv = (float)sqrt(var);
    float denom = __fadd_rn(stdv, 1e-5f);

    double s1 = 0.0, s2 = 0.0;
    for (int r = 0; r < 4; r++) {
        int s = r * 256 + t;
        float v;
        if (c < 3) {
            v = A[((size_t)b * SS + s) * 3 + c] / denom;
        } else {
            float ww = new_xyz[((size_t)b * SS + s) * 3 + (c - 3)];
            v = __fadd_rn(ww, ww);
        }
        lc[((size_t)b * 6 + c) * SS + s] = v;
        s1 += (double)v;
        s2 += (double)v * (double)v;
    }
#pragma unroll
    for (int off = 32; off > 0; off >>= 1) { s1 += __shfl_down(s1, off); s2 += __shfl_down(s2, off); }
    int wv = t >> 6, ln = t & 63;
    if (ln == 0) red[wv] = s1;
    __syncthreads();
    if (t == 0) atomicAdd(&bn1acc[c * 2 + 0], red[0] + red[1] + red[2] + red[3]);
    __syncthreads();
    if (ln == 0) red[wv] = s2;
    __syncthreads();
    if (t == 0) atomicAdd(&bn1acc[c * 2 + 1], red[0] + red[1] + red[2] + red[3]);
}

// ---------------------------------------------------------------------------
// K4a: per-batch: y = relu(BN1(lc)), then 6x6 safe cdist over S. 16 blocks.
// ---------------------------------------------------------------------------
__global__ __launch_bounds__(256) void cdist_kernel(const float* __restrict__ lc,
                                                    const double* __restrict__ bn1acc,
                                                    const float* __restrict__ params,
                                                    float* __restrict__ tf) {
    __shared__ float sy[6 * SS];
    const int b = blockIdx.x, t = threadIdx.x;
    float mean[6], sde[6], gg[6], bt[6];
    const double n = (double)BB * SS;
#pragma unroll
    for (int c = 0; c < 6; c++) {
        double m = bn1acc[c * 2 + 0] / n;
        double v = bn1acc[c * 2 + 1] / n - m * m;
        mean[c] = (float)m;
        sde[c] = sqrtf((float)v + 1e-5f);
        gg[c] = params[c];
        bt[c] = params[6 + c];
    }
    for (int r = 0; r < 24; r++) {
        int g = r * 256 + t;
        int c = g >> 10;
        float v = lc[(size_t)b * 6 * SS + g];
        float y = (v - mean[c]) / sde[c] * gg[c] + bt[c];
        sy[g] = fmaxf(y, 0.0f);
    }
    __syncthreads();
    if (t < 6) tf[b * 36 + t * 7] = 0.0f;

    const int w = t >> 6, lane = t & 63;
    const int PI[15] = {0,0,0,0,0,1,1,1,1,2,2,2,3,3,4};
    const int PJ[15] = {1,2,3,4,5,2,3,4,5,3,4,5,4,5,5};
    for (int r = 0; r < 4; r++) {
        int p = w + r * 4;
        if (p < 15) {
            int i = PI[p], j = PJ[p];
            float acc = 0.0f;
            for (int m2 = 0; m2 < 16; m2++) {
                int s = lane + m2 * 64;
                float d = sy[i * SS + s] - sy[j * SS + s];
                acc += d * d;
            }
#pragma unroll
            for (int off = 32; off > 0; off >>= 1) acc += __shfl_down(acc, off);
            if (lane == 0) {
                float v = acc > 0.0f ? sqrtf(acc) : 0.0f;
                const float FACTOR = 1.0f;
                tf[b * 36 + i * 6 + j] = (j == i + 1) ? v * FACTOR : v;
                tf[b * 36 + j * 6 + i] = v;
            }
        }
    }
}

// ---------------------------------------------------------------------------
// K4b: BN2 over batch per feature + relu -> out [16,36] (dtype per params[84]).
// ---------------------------------------------------------------------------
__global__ __launch_bounds__(64) void bn2_kernel(const float* __restrict__ tf,
                                                 const float* __restrict__ params,
                                                 void* __restrict__ out_raw) {
    int f = threadIdx.x;
    if (f >= 36) return;
    bool isbf = params[84] != 0.0f;
    float x[16]; float sum = 0.0f;
#pragma unroll
    for (int b = 0; b < 16; b++) { x[b] = tf[b * 36 + f]; sum += x[b]; }
    float mean = sum * 0.0625f;
    float vs = 0.0f;
#pragma unroll
    for (int b = 0; b < 16; b++) { float d = x[b] - mean; vs += d * d; }
    float var = vs * 0.0625f;
    float denom = sqrtf(var + 1e-5f);
    float g = params[12 + f], bb = params[48 + f];
#pragma unroll
    for (int b = 0; b < 16; b++) {
        float y = (x[b] - mean) / denom * g + bb;
        y = fmaxf(y, 0.0f);
        if (isbf) ((__hip_bfloat16*)out_raw)[b * 36 + f] = __float2bfloat16(y);
        else      ((float*)out_raw)[b * 36 + f] = y;
    }
}

// ---------------------------------------------------------------------------
// Workspace layout (bytes):
//   0        : xyzf     float[16*8192*3]   (1572864)
//   1572864  : new_xyz  float[16*1024*3]   (196608)
//   1769472  : A        float[16*1024*3]   (196608)
//   1966080  : lc       float[16*6*1024]   (393216)
//   2359296  : tfcw     float[16*36]       (2304)
//   2361600  : stats    double[14]
//   2361712  : params   float[85]
//   2362112  : qstats   double[16384*2]    (262144)
//   2624256  : slots    u32[16384]         (65536)  [fps->knn handshake]
// ---------------------------------------------------------------------------
extern "C" void kernel_launch(void* const* d_in, const int* in_sizes, int n_in,
                              void* d_out, int out_size, void* d_ws, size_t ws_size,
                              hipStream_t stream) {
    const void* xyz_raw = d_in[0];
    const void* g1r = d_in[1]; const void* b1r = d_in[2];
    const void* g2r = d_in[3]; const void* b2r = d_in[4];
    {
        const void* six[2] = {nullptr, nullptr}; int n6 = 0;
        const void* t36[2] = {nullptr, nullptr}; int n36 = 0;
        const void* big = nullptr;
        for (int i = 0; i < n_in; i++) {
            if (in_sizes[i] == BB * NN * 3) big = d_in[i];
            else if (in_sizes[i] == 6  && n6  < 2) six[n6++]  = d_in[i];
            else if (in_sizes[i] == 36 && n36 < 2) t36[n36++] = d_in[i];
        }
        if (big && n6 == 2 && n36 == 2) {
            xyz_raw = big; g1r = six[0]; b1r = six[1]; g2r = t36[0]; b2r = t36[1];
        }
    }

    char* ws = (char*)d_ws;
    float* xyzf    = (float*)(ws + 0);
    float* new_xyz = (float*)(ws + 1572864);
    float* A       = (float*)(ws + 1769472);
    float* lc      = (float*)(ws + 1966080);
    float* tf      = (float*)(ws + 2359296);
    double* stats  = (double*)(ws + 2361600);
    double* bn1acc = stats + 2;
    float* params  = (float*)(ws + 2361712);
    double* qstats = (double*)(ws + 2362112);
    unsigned* slots = (unsigned*)(ws + 2624256);

    hipMemsetAsync(stats, 0, 14 * sizeof(double), stream);
    hipMemsetAsync(slots, 0, BB * SS * sizeof(unsigned), stream);
    hipLaunchKernelGGL(convert_kernel, dim3(512), dim3(256), 0, stream,
                       xyz_raw, g1r, b1r, g2r, b2r, xyzf, params, d_out);
    hipLaunchKernelGGL(fps_knn_kernel,      dim3(NBLK), dim3(512), 0, stream,
                       xyzf, new_xyz, slots, A, qstats);
    hipLaunchKernelGGL(reduce_stats_kernel, dim3(1),    dim3(256), 0, stream, qstats, stats);
    hipLaunchKernelGGL(lc_kernel,           dim3(96),   dim3(256), 0, stream, new_xyz, A, stats, lc, bn1acc);
    hipLaunchKernelGGL(cdist_kernel,        dim3(16),   dim3(256), 0, stream, lc, bn1acc, params, tf);
    hipLaunchKernelGGL(bn2_kernel,          dim3(1),    dim3(64),  0, stream, tf, params, d_out);

    (void)in_sizes; (void)n_in; (void)out_size; (void)ws_size;
}

// Round 15
// 1193.045 us; speedup vs baseline: 2.7532x; 1.1686x over previous
//
#include <hip/hip_runtime.h>
#include <hip/hip_bf16.h>

// Problem constants (from reference)
constexpr int BB = 16;     // batches
constexpr int NN = 8192;   // points
constexpr int SS = 1024;   // samples (FPS)
constexpr int KK = 32;     // kNN
constexpr int BUFC = 256;  // per-wave candidate buffer (keys <= That)

__device__ __forceinline__ float b2f(__hip_bfloat16 h) { return __bfloat162float(h); }

// Monotone map f32 -> u32 (order-preserving, bijective; d is never -0 here).
__device__ __forceinline__ unsigned mkey32(float d) {
    unsigned u = __float_as_uint(d);
    return u ^ (0x80000000u | (unsigned)((int)u >> 31));
}

// Deterministic distance key for point idx vs query (qx,qy,qz,qq).
// Same expression sequence every call -> bit-identical results (IEEE, no FMA).
__device__ __forceinline__ unsigned long long dist_key(const float* __restrict__ pb,
                                                       int idx, float qx, float qy,
                                                       float qz, float qq) {
    float px = pb[idx * 3 + 0];
    float py = pb[idx * 3 + 1];
    float pz = pb[idx * 3 + 2];
    float dot = __fadd_rn(__fadd_rn(__fmul_rn(qx, px), __fmul_rn(qy, py)), __fmul_rn(qz, pz));
    float pp  = __fadd_rn(__fadd_rn(__fmul_rn(px, px), __fmul_rn(py, py)), __fmul_rn(pz, pz));
    float d = __fadd_rn(__fadd_rn(__fmul_rn(-2.0f, dot), qq), pp);
    return ((unsigned long long)mkey32(d) << 32) | (unsigned)idx;
}

// DPP lane-move of a u64 (both halves move identically).
template <int CTRL, int RMASK>
__device__ __forceinline__ unsigned long long dppmove_u64(unsigned long long v) {
    int lo = (int)(unsigned)v, hi = (int)(unsigned)(v >> 32);
    int nlo = __builtin_amdgcn_update_dpp(lo, lo, CTRL, RMASK, 0xf, false);
    int nhi = __builtin_amdgcn_update_dpp(hi, hi, CTRL, RMASK, 0xf, false);
    return ((unsigned long long)(unsigned)nhi << 32) | (unsigned)nlo;
}

__device__ __forceinline__ unsigned long long u64max(unsigned long long a,
                                                     unsigned long long b) {
    return a > b ? a : b;
}

// Wave64 max-reduce via DPP. Lane 63 holds the max.
__device__ __forceinline__ unsigned long long wave_max_dpp(unsigned long long k) {
    k = u64max(k, dppmove_u64<0x121, 0xf>(k));  // row_ror:1
    k = u64max(k, dppmove_u64<0x122, 0xf>(k));  // row_ror:2
    k = u64max(k, dppmove_u64<0x124, 0xf>(k));  // row_ror:4
    k = u64max(k, dppmove_u64<0x128, 0xf>(k));  // row_ror:8
    k = u64max(k, dppmove_u64<0x142, 0xa>(k));  // row_bcast:15 -> rows 1,3
    k = u64max(k, dppmove_u64<0x143, 0xc>(k));  // row_bcast:31 -> rows 2,3
    return k;
}

// Cross-lane bitonic sort of 64 u64 keys (ascending); lane i ends with i-th smallest.
__device__ __forceinline__ unsigned long long bitonic64(unsigned long long v, int lane) {
#pragma unroll
    for (int k = 2; k <= 64; k <<= 1) {
#pragma unroll
        for (int j = k >> 1; j > 0; j >>= 1) {
            unsigned long long p = __shfl_xor(v, j);
            bool up = ((lane & k) == 0);
            bool lower = ((lane & j) == 0);
            bool take_min = (up == lower);
            v = take_min ? (p < v ? p : v) : (p > v ? p : v);
        }
    }
    return v;
}

// ---------------------------------------------------------------------------
// K0: dtype detection + upcast to f32 workspace + sentinel fill of d_out.
// ---------------------------------------------------------------------------
__global__ __launch_bounds__(256) void convert_kernel(
    const void* __restrict__ xyz_raw, const void* __restrict__ g1r,
    const void* __restrict__ b1r, const void* __restrict__ g2r,
    const void* __restrict__ b2r, float* __restrict__ xyzf,
    float* __restrict__ params, void* __restrict__ out_raw) {
    const unsigned short* u = (const unsigned short*)xyz_raw;
    unsigned short s = u[2 * (threadIdx.x & 63)];
    int e = (s >> 7) & 0xFF;
    unsigned long long m = __ballot(e >= 100 && e <= 140);
    bool isbf = __popcll(m) > 48;

    const int NT = BB * NN * 3;
    int tid = blockIdx.x * blockDim.x + threadIdx.x;
    int stride = gridDim.x * blockDim.x;
    if (isbf) {
        const __hip_bfloat16* p = (const __hip_bfloat16*)xyz_raw;
        for (int i = tid; i < NT; i += stride) xyzf[i] = b2f(p[i]);
    } else {
        const float* p = (const float*)xyz_raw;
        for (int i = tid; i < NT; i += stride) xyzf[i] = p[i];
    }
    if (blockIdx.x == 0 && threadIdx.x < 85) {
        int t = threadIdx.x;
        if (t == 84) {
            params[84] = isbf ? 1.0f : 0.0f;
        } else {
            const void* src; int off;
            if (t < 6)       { src = g1r; off = t; }
            else if (t < 12) { src = b1r; off = t - 6; }
            else if (t < 48) { src = g2r; off = t - 12; }
            else             { src = b2r; off = t - 48; }
            params[t] = isbf ? b2f(((const __hip_bfloat16*)src)[off])
                             : ((const float*)src)[off];
        }
    }
    if (blockIdx.x == 1 && threadIdx.x < 64) {
        for (int i = threadIdx.x; i < 576; i += 64) {
            if (isbf) ((__hip_bfloat16*)out_raw)[i] = __float2bfloat16(1.0f);
            else      ((float*)out_raw)[i] = 1.0f;
        }
    }
}

// ---------------------------------------------------------------------------
// K1: Farthest point sampling — r7/r10 configuration (measured best: 948 us).
// One block per batch, 512 threads, 16 pts/thread in registers. Exact vs np:
// no FMA, argmax ties break to lowest index via key = (dist_bits<<32)|~idx.
// DPP wave reduce -> LDS(8) -> all-thread scan -> centroid from LDS sxyz.
// amdgpu_waves_per_eu(2,2): pins allocator budget so px/py/pz/ds stay in
// arch VGPRs (r5/r6: launch_bounds alone ignored -> spill).
// r8/r9: multi-CU FPS loses to single-CU (cross-CU handshake ~1.4 us/step).
// r14: fusing knn under fps stretches fps 948->1300 (publish-store drain +
// full-chip contention on the serial producer) — fusion abandoned.
// ---------------------------------------------------------------------------
__global__ __attribute__((amdgpu_flat_work_group_size(512, 512)))
__attribute__((amdgpu_waves_per_eu(2, 2)))
void fps_kernel(const float* __restrict__ xyzf, float* __restrict__ new_xyz) {
    constexpr int T = 512, P = NN / T;  // 16 points per thread, idx = t + j*T
    const int b = blockIdx.x, t = threadIdx.x;
    const float* xb = xyzf + (size_t)b * NN * 3;

    __shared__ float sxyz[NN * 3];          // 96 KB coord table
    __shared__ unsigned long long skey[2][8];

    float px[P], py[P], pz[P], ds[P];
#pragma unroll
    for (int j = 0; j < P; j++) {
        int p = t + j * T;
        px[j] = xb[p * 3 + 0];
        py[j] = xb[p * 3 + 1];
        pz[j] = xb[p * 3 + 2];
        ds[j] = 1e10f;
    }
    for (int i = t; i < NN * 3; i += T) sxyz[i] = xb[i];  // stage coords

    float cx = xb[0], cy = xb[1], cz = xb[2];
    if (t == 0) {
        float* o = new_xyz + (size_t)b * SS * 3;
        o[0] = cx; o[1] = cy; o[2] = cz;
    }
    const int wave = t >> 6, lane = t & 63;
    __syncthreads();   // sxyz visible before first centroid lookup

    for (int step = 1; step < SS; step++) {
        float bv = -1.0f; int bj = 0;
#pragma unroll
        for (int j = 0; j < P; j++) {
            float dx = __fsub_rn(px[j], cx);
            float dy = __fsub_rn(py[j], cy);
            float dz = __fsub_rn(pz[j], cz);
            float d = __fadd_rn(__fadd_rn(__fmul_rn(dx, dx), __fmul_rn(dy, dy)), __fmul_rn(dz, dz));
            float mm = fminf(ds[j], d);
            ds[j] = mm;
            if (mm > bv) { bv = mm; bj = j; }   // ascending j: first-max kept (lowest idx)
        }
        unsigned idx = (unsigned)(t + bj * T);
        unsigned long long key =
            ((unsigned long long)__float_as_uint(bv) << 32) | (unsigned)(~idx);

        key = wave_max_dpp(key);
        const int par = step & 1;
        if (lane == 63) skey[par][wave] = key;
        __syncthreads();

        unsigned long long k0 = u64max(skey[par][0], skey[par][1]);
        unsigned long long k1 = u64max(skey[par][2], skey[par][3]);
        unsigned long long k2 = u64max(skey[par][4], skey[par][5]);
        unsigned long long k3 = u64max(skey[par][6], skey[par][7]);
        unsigned long long bk = u64max(u64max(k0, k1), u64max(k2, k3));

        unsigned gidx = ~(unsigned)bk;      // winner point index (global in batch)
        cx = sxyz[gidx * 3 + 0];            // LDS broadcast (same bits as global)
        cy = sxyz[gidx * 3 + 1];
        cz = sxyz[gidx * 3 + 2];
        if (t == 0) {
            float* o = new_xyz + ((size_t)b * SS + step) * 3;
            o[0] = cx; o[1] = cy; o[2] = cz;
        }
    }
}

// ---------------------------------------------------------------------------
// K2 (RECOMPUTE): kNN via exact threshold selection, one wave per query,
// NO per-lane key array.
// r13/r14 LESSON: mk[128] spilled to scratch -> 2.2 GB HBM traffic (32KB per
// query written+read); this was the entire ~300 us knn cost in r4-r10.
// Fix: pass 1 tracks only the lane-min key; pass 2 RECOMPUTES each key for
// the compaction test. IEEE ops on immutable inputs -> bit-identical keys ->
// selection unchanged (r14: absmax identical). Extra VALU (~1 extra pass
// over L2-resident cloud) is far cheaper than scratch round-trips.
// ---------------------------------------------------------------------------
__global__ __launch_bounds__(256, 2) void knn_kernel(const float* __restrict__ xyzf,
                                                     const float* __restrict__ new_xyz,
                                                     float* __restrict__ A,
                                                     double* __restrict__ qstats) {
    __shared__ unsigned long long buf[4][BUFC];
    const int t = threadIdx.x;
    const int lane = t & 63, wv = t >> 6;
    const int w = blockIdx.x * 4 + wv;          // global wave id = query id
    const int b = w >> 10, s = w & 1023;

    const float* q = new_xyz + ((size_t)b * SS + s) * 3;
    float qx = q[0], qy = q[1], qz = q[2];
    float qq = __fadd_rn(__fadd_rn(__fmul_rn(qx, qx), __fmul_rn(qy, qy)), __fmul_rn(qz, qz));

    const float* pb = xyzf + (size_t)b * NN * 3;
    const unsigned long long ltmask = (1ull << lane) - 1ull;

    // pass 1: lane-min key only (no storage)
    unsigned long long lmin = ~0ull;
    for (int j = 0; j < 128; j++) {
        unsigned long long key = dist_key(pb, j * 64 + lane, qx, qy, qz, qq);
        lmin = key < lmin ? key : lmin;
    }

    unsigned long long vs = bitonic64(lmin, lane);
    unsigned long long That = __shfl(vs, 31);

    // pass 2: recompute keys, compact keys <= That into LDS
    for (int i = lane; i < BUFC; i += 64) buf[wv][i] = ~0ull;
    int base = 0;
    for (int j = 0; j < 128; j++) {
        unsigned long long key = dist_key(pb, j * 64 + lane, qx, qy, qz, qq);
        bool f = key <= That;
        unsigned long long bal = __ballot(f);
        int pos = base + __popcll(bal & ltmask);
        if (f && pos < BUFC) buf[wv][pos] = key;
        base += __popcll(bal);
    }

    // rare recovery: tighten threshold (recompute inside search)
    if (base > BUFC) {
        unsigned lo = 0, hi = (unsigned)(That >> 32);
        for (int it = 0; it < 32; it++) {
            unsigned mid = lo + ((hi - lo) >> 1);
            int c = 0;
            for (int j = 0; j < 128; j++) {
                unsigned long long key = dist_key(pb, j * 64 + lane, qx, qy, qz, qq);
                c += ((unsigned)(key >> 32) <= mid) ? 1 : 0;
            }
#pragma unroll
            for (int o = 32; o > 0; o >>= 1) c += __shfl_xor(c, o);
            if (c >= 32) hi = mid; else lo = mid + 1;
        }
        That = ((unsigned long long)hi << 32) | 0xFFFFFFFFull;
        for (int i = lane; i < BUFC; i += 64) buf[wv][i] = ~0ull;
        base = 0;
        for (int j = 0; j < 128; j++) {
            unsigned long long key = dist_key(pb, j * 64 + lane, qx, qy, qz, qq);
            bool f = key <= That;
            unsigned long long bal = __ballot(f);
            int pos = base + __popcll(bal & ltmask);
            if (f && pos < BUFC) buf[wv][pos] = key;
            base += __popcll(bal);
        }
        if (base > BUFC) base = BUFC;
    }

    int M = base;
    unsigned long long kept = ~0ull;
    if (M <= 64) {
        unsigned long long v = (lane < M) ? buf[wv][lane] : ~0ull;
        v = bitonic64(v, lane);
        kept = v;
    } else {
        unsigned long long c0 = buf[wv][lane];
        unsigned long long c1 = buf[wv][64 + lane];
        unsigned long long c2 = buf[wv][128 + lane];
        unsigned long long c3 = buf[wv][192 + lane];
        for (int r = 0; r < KK; r++) {
            unsigned long long m01 = c0 < c1 ? c0 : c1;
            unsigned long long m23 = c2 < c3 ? c2 : c3;
            unsigned long long mm = m01 < m23 ? m01 : m23;
#pragma unroll
            for (int o = 32; o > 0; o >>= 1) {
                unsigned long long t2 = __shfl_xor(mm, o);
                mm = t2 < mm ? t2 : mm;
            }
            if (lane == r) kept = mm;
            c0 = (c0 == mm) ? ~0ull : c0;
            c1 = (c1 == mm) ? ~0ull : c1;
            c2 = (c2 == mm) ? ~0ull : c2;
            c3 = (c3 == mm) ? ~0ull : c3;
        }
    }

    bool act = (lane < KK);
    float gx = 0.0f, gy = 0.0f, gz = 0.0f;
    if (act) {
        unsigned nidx = (unsigned)kept;
        gx = pb[nidx * 3 + 0];
        gy = pb[nidx * 3 + 1];
        gz = pb[nidx * 3 + 2];
    }
    float dx = __fsub_rn(gx, qx);
    float dy = __fsub_rn(gy, qy);
    float dz = __fsub_rn(gz, qz);
    float mx = act ? dx : -3.402823466e38f;
    float my = act ? dy : -3.402823466e38f;
    float mz = act ? dz : -3.402823466e38f;
    float sx = act ? dx : 0.0f;
    float sy = act ? dy : 0.0f;
    float sz = act ? dz : 0.0f;
    double s1 = act ? ((double)dx + (double)dy + (double)dz) : 0.0;
    double s2 = act ? ((double)dx * dx + (double)dy * dy + (double)dz * dz) : 0.0;
#pragma unroll
    for (int o = 32; o > 0; o >>= 1) {
        mx = fmaxf(mx, __shfl_xor(mx, o));
        my = fmaxf(my, __shfl_xor(my, o));
        mz = fmaxf(mz, __shfl_xor(mz, o));
        sx += __shfl_xor(sx, o);
        sy += __shfl_xor(sy, o);
        sz += __shfl_xor(sz, o);
        s1 += __shfl_xor(s1, o);
        s2 += __shfl_xor(s2, o);
    }
    if (lane == 0) {
        float* a = A + ((size_t)b * SS + s) * 3;
        a[0] = __fadd_rn(mx, __fmul_rn(sx, 0.03125f));
        a[1] = __fadd_rn(my, __fmul_rn(sy, 0.03125f));
        a[2] = __fadd_rn(mz, __fmul_rn(sz, 0.03125f));
        qstats[2 * w + 0] = s1;
        qstats[2 * w + 1] = s2;
    }
}

// ---------------------------------------------------------------------------
// K2b: reduce per-query stats -> global stats[0..1]. One block.
// ---------------------------------------------------------------------------
__global__ __launch_bounds__(256) void reduce_stats_kernel(const double* __restrict__ qstats,
                                                           double* __restrict__ stats) {
    __shared__ double r1[4], r2[4];
    int t = threadIdx.x;
    double a = 0.0, bsum = 0.0;
    for (int i = t; i < BB * SS; i += 256) { a += qstats[2 * i]; bsum += qstats[2 * i + 1]; }
#pragma unroll
    for (int o = 32; o > 0; o >>= 1) { a += __shfl_xor(a, o); bsum += __shfl_xor(bsum, o); }
    int wv = t >> 6, ln = t & 63;
    if (ln == 0) { r1[wv] = a; r2[wv] = bsum; }
    __syncthreads();
    if (t == 0) {
        stats[0] = r1[0] + r1[1] + r1[2] + r1[3];
        stats[1] = r2[0] + r2[1] + r2[2] + r2[3];
    }
}

// ---------------------------------------------------------------------------
// K3: lc[b,c,s]: c<3 -> A/(std+1e-5); c>=3 -> 2*new_xyz. Accumulate BN1 sums.
// ---------------------------------------------------------------------------
__global__ __launch_bounds__(256) void lc_kernel(const float* __restrict__ new_xyz,
                                                 const float* __restrict__ A,
                                                 const double* __restrict__ stats,
                                                 float* __restrict__ lc,
                                                 double* __restrict__ bn1acc) {
    __shared__ double red[4];
    const int b = blockIdx.x / 6, c = blockIdx.x % 6;
    const int t = threadIdx.x;
    const double n = (double)BB * SS * KK * 3;
    double sd = stats[0], sq = stats[1];
    double var = (sq - sd * sd / n) / (n - 1.0);
    float stdv = (float)sqrt(var);
    float denom = __fadd_rn(stdv, 1e-5f);

    double s1 = 0.0, s2 = 0.0;
    for (int r = 0; r < 4; r++) {
        int s = r * 256 + t;
        float v;
        if (c < 3) {
            v = A[((size_t)b * SS + s) * 3 + c] / denom;
        } else {
            float ww = new_xyz[((size_t)b * SS + s) * 3 + (c - 3)];
            v = __fadd_rn(ww, ww);
        }
        lc[((size_t)b * 6 + c) * SS + s] = v;
        s1 += (double)v;
        s2 += (double)v * (double)v;
    }
#pragma unroll
    for (int off = 32; off > 0; off >>= 1) { s1 += __shfl_down(s1, off); s2 += __shfl_down(s2, off); }
    int wv = t >> 6, ln = t & 63;
    if (ln == 0) red[wv] = s1;
    __syncthreads();
    if (t == 0) atomicAdd(&bn1acc[c * 2 + 0], red[0] + red[1] + red[2] + red[3]);
    __syncthreads();
    if (ln == 0) red[wv] = s2;
    __syncthreads();
    if (t == 0) atomicAdd(&bn1acc[c * 2 + 1], red[0] + red[1] + red[2] + red[3]);
}

// ---------------------------------------------------------------------------
// K4a: per-batch: y = relu(BN1(lc)), then 6x6 safe cdist over S. 16 blocks.
// ---------------------------------------------------------------------------
__global__ __launch_bounds__(256) void cdist_kernel(const float* __restrict__ lc,
                                                    const double* __restrict__ bn1acc,
                                                    const float* __restrict__ params,
                                                    float* __restrict__ tf) {
    __shared__ float sy[6 * SS];
    const int b = blockIdx.x, t = threadIdx.x;
    float mean[6], sde[6], gg[6], bt[6];
    const double n = (double)BB * SS;
#pragma unroll
    for (int c = 0; c < 6; c++) {
        double m = bn1acc[c * 2 + 0] / n;
        double v = bn1acc[c * 2 + 1] / n - m * m;
        mean[c] = (float)m;
        sde[c] = sqrtf((float)v + 1e-5f);
        gg[c] = params[c];
        bt[c] = params[6 + c];
    }
    for (int r = 0; r < 24; r++) {
        int g = r * 256 + t;
        int c = g >> 10;
        float v = lc[(size_t)b * 6 * SS + g];
        float y = (v - mean[c]) / sde[c] * gg[c] + bt[c];
        sy[g] = fmaxf(y, 0.0f);
    }
    __syncthreads();
    if (t < 6) tf[b * 36 + t * 7] = 0.0f;

    const int w = t >> 6, lane = t & 63;
    const int PI[15] = {0,0,0,0,0,1,1,1,1,2,2,2,3,3,4};
    const int PJ[15] = {1,2,3,4,5,2,3,4,5,3,4,5,4,5,5};
    for (int r = 0; r < 4; r++) {
        int p = w + r * 4;
        if (p < 15) {
            int i = PI[p], j = PJ[p];
            float acc = 0.0f;
            for (int m2 = 0; m2 < 16; m2++) {
                int s = lane + m2 * 64;
                float d = sy[i * SS + s] - sy[j * SS + s];
                acc += d * d;
            }
#pragma unroll
            for (int off = 32; off > 0; off >>= 1) acc += __shfl_down(acc, off);
            if (lane == 0) {
                float v = acc > 0.0f ? sqrtf(acc) : 0.0f;
                const float FACTOR = 1.0f;
                tf[b * 36 + i * 6 + j] = (j == i + 1) ? v * FACTOR : v;
                tf[b * 36 + j * 6 + i] = v;
            }
        }
    }
}

// ---------------------------------------------------------------------------
// K4b: BN2 over batch per feature + relu -> out [16,36] (dtype per params[84]).
// ---------------------------------------------------------------------------
__global__ __launch_bounds__(64) void bn2_kernel(const float* __restrict__ tf,
                                                 const float* __restrict__ params,
                                                 void* __restrict__ out_raw) {
    int f = threadIdx.x;
    if (f >= 36) return;
    bool isbf = params[84] != 0.0f;
    float x[16]; float sum = 0.0f;
#pragma unroll
    for (int b = 0; b < 16; b++) { x[b] = tf[b * 36 + f]; sum += x[b]; }
    float mean = sum * 0.0625f;
    float vs = 0.0f;
#pragma unroll
    for (int b = 0; b < 16; b++) { float d = x[b] - mean; vs += d * d; }
    float var = vs * 0.0625f;
    float denom = sqrtf(var + 1e-5f);
    float g = params[12 + f], bb = params[48 + f];
#pragma unroll
    for (int b = 0; b < 16; b++) {
        float y = (x[b] - mean) / denom * g + bb;
        y = fmaxf(y, 0.0f);
        if (isbf) ((__hip_bfloat16*)out_raw)[b * 36 + f] = __float2bfloat16(y);
        else      ((float*)out_raw)[b * 36 + f] = y;
    }
}

// ---------------------------------------------------------------------------
// Workspace layout (bytes):
//   0        : xyzf     float[16*8192*3]   (1572864)
//   1572864  : new_xyz  float[16*1024*3]   (196608)
//   1769472  : A        float[16*1024*3]   (196608)
//   1966080  : lc       float[16*6*1024]   (393216)
//   2359296  : tfcw     float[16*36]       (2304)
//   2361600  : stats    double[14]
//   2361712  : params   float[85]
//   2362112  : qstats   double[16384*2]    (262144)
// ---------------------------------------------------------------------------
extern "C" void kernel_launch(void* const* d_in, const int* in_sizes, int n_in,
                              void* d_out, int out_size, void* d_ws, size_t ws_size,
                              hipStream_t stream) {
    const void* xyz_raw = d_in[0];
    const void* g1r = d_in[1]; const void* b1r = d_in[2];
    const void* g2r = d_in[3]; const void* b2r = d_in[4];
    {
        const void* six[2] = {nullptr, nullptr}; int n6 = 0;
        const void* t36[2] = {nullptr, nullptr}; int n36 = 0;
        const void* big = nullptr;
        for (int i = 0; i < n_in; i++) {
            if (in_sizes[i] == BB * NN * 3) big = d_in[i];
            else if (in_sizes[i] == 6  && n6  < 2) six[n6++]  = d_in[i];
            else if (in_sizes[i] == 36 && n36 < 2) t36[n36++] = d_in[i];
        }
        if (big && n6 == 2 && n36 == 2) {
            xyz_raw = big; g1r = six[0]; b1r = six[1]; g2r = t36[0]; b2r = t36[1];
        }
    }

    char* ws = (char*)d_ws;
    float* xyzf    = (float*)(ws + 0);
    float* new_xyz = (float*)(ws + 1572864);
    float* A       = (float*)(ws + 1769472);
    float* lc      = (float*)(ws + 1966080);
    float* tf      = (float*)(ws + 2359296);
    double* stats  = (double*)(ws + 2361600);
    double* bn1acc = stats + 2;
    float* params  = (float*)(ws + 2361712);
    double* qstats = (double*)(ws + 2362112);

    hipMemsetAsync(stats, 0, 14 * sizeof(double), stream);
    hipLaunchKernelGGL(convert_kernel, dim3(512), dim3(256), 0, stream,
                       xyz_raw, g1r, b1r, g2r, b2r, xyzf, params, d_out);
    hipLaunchKernelGGL(fps_kernel,          dim3(16),   dim3(512), 0, stream, xyzf, new_xyz);
    hipLaunchKernelGGL(knn_kernel,          dim3(4096), dim3(256), 0, stream, xyzf, new_xyz, A, qstats);
    hipLaunchKernelGGL(reduce_stats_kernel, dim3(1),    dim3(256), 0, stream, qstats, stats);
    hipLaunchKernelGGL(lc_kernel,           dim3(96),   dim3(256), 0, stream, new_xyz, A, stats, lc, bn1acc);
    hipLaunchKernelGGL(cdist_kernel,        dim3(16),   dim3(256), 0, stream, lc, bn1acc, params, tf);
    hipLaunchKernelGGL(bn2_kernel,          dim3(1),    dim3(64),  0, stream, tf, params, d_out);

    (void)in_sizes; (void)n_in; (void)out_size; (void)ws_size;
}